// Round 1
// baseline (499.932 us; speedup 1.0000x reference)
//
#include <hip/hip_runtime.h>
#include <hip/hip_bf16.h>

#define BB 128
#define TT 512
#define NN 200
#define HH 128
static constexpr float BN_EPS_C = 1e-5f;
static constexpr int ROWS_TOT = BB * NN; // 25600

// ---------------------------------------------------------------- utilities
__global__ void zero_kernel(float* __restrict__ p, int n) {
    int i = blockIdx.x * blockDim.x + threadIdx.x;
    if (i < n) p[i] = 0.f;
}

// per-(b,n) mean over T and inverse centered-norm rsqrt(sum((x-m)^2))
__global__ __launch_bounds__(256) void mean_invd_kernel(
        const float* __restrict__ X, float* __restrict__ meanv, float* __restrict__ invd) {
    int b = blockIdx.x;
    int n = threadIdx.x;
    if (n >= NN) return;
    const float* xb = X + (size_t)b * TT * NN + n;
    float s = 0.f;
    #pragma unroll 8
    for (int t = 0; t < TT; ++t) s += xb[(size_t)t * NN];
    float m = s * (1.f / TT);
    float ss = 0.f;
    #pragma unroll 8
    for (int t = 0; t < TT; ++t) { float d = xb[(size_t)t * NN] - m; ss = fmaf(d, d, ss); }
    meanv[b * NN + n] = m;
    invd[b * NN + n] = (ss > 0.f) ? rsqrtf(ss) : 0.f;
}

// ---------------------------------------------------------------- corrcoef
// fc1[b,i,j] = clip( sum_t xm[t,i]*xm[t,j] * invd_i * invd_j , -1, 1)
#define TK 16
__global__ __launch_bounds__(256) void corr_kernel(
        const float* __restrict__ X, const float* __restrict__ meanv,
        const float* __restrict__ invd, float* __restrict__ fc1) {
    int b  = blockIdx.z;
    int i0 = blockIdx.x * 64;
    int j0 = blockIdx.y * 64;
    __shared__ float rowT[TK][64];
    __shared__ float colT[TK][64];
    int tid = threadIdx.x;
    int ii  = tid & 63;
    int tl4 = (tid >> 6) * 4;          // 0,4,8,12
    int gi = i0 + ii, gj = j0 + ii;
    const float* xb = X + (size_t)b * TT * NN;
    float mi = (gi < NN) ? meanv[b * NN + gi] : 0.f;
    float mj = (gj < NN) ? meanv[b * NN + gj] : 0.f;
    int tr = tid >> 4, tc = tid & 15;  // 16x16 threads, 4x4 micro-tile
    float acc[4][4] = {};
    for (int t0 = 0; t0 < TT; t0 += TK) {
        #pragma unroll
        for (int j = 0; j < 4; ++j) {
            int t = t0 + tl4 + j;
            rowT[tl4 + j][ii] = (gi < NN) ? (xb[(size_t)t * NN + gi] - mi) : 0.f;
            colT[tl4 + j][ii] = (gj < NN) ? (xb[(size_t)t * NN + gj] - mj) : 0.f;
        }
        __syncthreads();
        #pragma unroll
        for (int k = 0; k < TK; ++k) {
            float4 av = *reinterpret_cast<const float4*>(&rowT[k][tr * 4]);
            float4 bv = *reinterpret_cast<const float4*>(&colT[k][tc * 4]);
            const float a4[4] = {av.x, av.y, av.z, av.w};
            const float b4[4] = {bv.x, bv.y, bv.z, bv.w};
            #pragma unroll
            for (int u = 0; u < 4; ++u)
                #pragma unroll
                for (int v = 0; v < 4; ++v)
                    acc[u][v] = fmaf(a4[u], b4[v], acc[u][v]);
        }
        __syncthreads();
    }
    float di[4], dj[4];
    #pragma unroll
    for (int u = 0; u < 4; ++u) { int i = i0 + tr * 4 + u; di[u] = (i < NN) ? invd[b * NN + i] : 0.f; }
    #pragma unroll
    for (int v = 0; v < 4; ++v) { int j = j0 + tc * 4 + v; dj[v] = (j < NN) ? invd[b * NN + j] : 0.f; }
    #pragma unroll
    for (int u = 0; u < 4; ++u) {
        int i = i0 + tr * 4 + u;
        if (i >= NN) continue;
        #pragma unroll
        for (int v = 0; v < 4; ++v) {
            int j = j0 + tc * 4 + v;
            if (j >= NN) continue;
            float val = acc[u][v] * di[u] * dj[v];
            val = fminf(1.f, fmaxf(-1.f, val));
            fc1[((size_t)b * NN + i) * NN + j] = val;
        }
    }
}

// ---------------------------------------------------------------- flat GEMM
// Out[M=25600, 128] = xform(A)[M, KDIM] @ W[KDIM, 128] (+bias) (+stats)
// XFORM: 0=identity, 1=abs, 2=bn(scale,shift)+relu  (bnp[ch], bnp[128+ch])
template<int KDIM, int XFORM, bool STATS, bool HASBIAS>
__global__ __launch_bounds__(256) void gemm_bw_kernel(
        const float* __restrict__ A, const float* __restrict__ W,
        const float* __restrict__ bnp, const float* __restrict__ bias,
        float* __restrict__ Out, float* __restrict__ stats) {
    __shared__ float A_l[64][33];
    __shared__ float W_l[32][128];
    __shared__ float ssum[128], ssq[128];
    int m0  = blockIdx.x * 64;
    int tid = threadIdx.x;
    int rt4 = tid >> 4;            // 0..15 -> 4 rows each
    int ct8 = tid & 15;            // 0..15 -> 8 cols each
    int lrow = tid >> 2;           // A-load: row 0..63
    int lk   = (tid & 3) * 8;      // A-load: k start
    float acc[4][8] = {};
    for (int k0 = 0; k0 < KDIM; k0 += 32) {
        int kc = min(32, KDIM - k0);
        #pragma unroll
        for (int j = 0; j < 8; ++j) {
            int kk = lk + j;
            float v = 0.f;
            if (kk < kc) {
                v = A[(size_t)(m0 + lrow) * KDIM + k0 + kk];
                if (XFORM == 1) v = fabsf(v);
                if (XFORM == 2) { int ch = k0 + kk; v = fmaxf(fmaf(v, bnp[ch], bnp[128 + ch]), 0.f); }
            }
            A_l[lrow][kk] = v;
        }
        #pragma unroll
        for (int q = 0; q < 4; ++q) {
            int fi = (q * 256 + tid) * 4;
            int kk = fi >> 7, cc = fi & 127;
            float4 wv = make_float4(0.f, 0.f, 0.f, 0.f);
            if (kk < kc) wv = *reinterpret_cast<const float4*>(&W[(size_t)(k0 + kk) * 128 + cc]);
            *reinterpret_cast<float4*>(&W_l[kk][cc]) = wv;
        }
        __syncthreads();
        #pragma unroll
        for (int k = 0; k < 32; ++k) {
            float a4[4];
            #pragma unroll
            for (int u = 0; u < 4; ++u) a4[u] = A_l[rt4 * 4 + u][k];
            float4 w0 = *reinterpret_cast<const float4*>(&W_l[k][ct8 * 8]);
            float4 w1 = *reinterpret_cast<const float4*>(&W_l[k][ct8 * 8 + 4]);
            const float w8[8] = {w0.x, w0.y, w0.z, w0.w, w1.x, w1.y, w1.z, w1.w};
            #pragma unroll
            for (int u = 0; u < 4; ++u)
                #pragma unroll
                for (int v = 0; v < 8; ++v)
                    acc[u][v] = fmaf(a4[u], w8[v], acc[u][v]);
        }
        __syncthreads();
    }
    float bsv[8] = {};
    if (HASBIAS) {
        #pragma unroll
        for (int v = 0; v < 8; ++v) bsv[v] = bias[ct8 * 8 + v];
    }
    float csum[8] = {}, csq[8] = {};
    #pragma unroll
    for (int u = 0; u < 4; ++u) {
        int m = m0 + rt4 * 4 + u;
        float o[8];
        #pragma unroll
        for (int v = 0; v < 8; ++v) o[v] = acc[u][v] + bsv[v];
        float4 o0 = make_float4(o[0], o[1], o[2], o[3]);
        float4 o1 = make_float4(o[4], o[5], o[6], o[7]);
        *reinterpret_cast<float4*>(&Out[(size_t)m * 128 + ct8 * 8])     = o0;
        *reinterpret_cast<float4*>(&Out[(size_t)m * 128 + ct8 * 8 + 4]) = o1;
        if (STATS) {
            #pragma unroll
            for (int v = 0; v < 8; ++v) { csum[v] += o[v]; csq[v] = fmaf(o[v], o[v], csq[v]); }
        }
    }
    if (STATS) {
        if (tid < 128) { ssum[tid] = 0.f; ssq[tid] = 0.f; }
        __syncthreads();
        #pragma unroll
        for (int v = 0; v < 8; ++v) {
            atomicAdd(&ssum[ct8 * 8 + v], csum[v]);
            atomicAdd(&ssq[ct8 * 8 + v], csq[v]);
        }
        __syncthreads();
        if (tid < 128) { atomicAdd(&stats[tid], ssum[tid]); atomicAdd(&stats[128 + tid], ssq[tid]); }
    }
}

// ---------------------------------------------------------------- mask GEMM
// Out[b, m, c] = sum_k (fc1[b,m,k]!=0) * P[b,k,c] + eps*P[b,m,c] + bias[c]; + stats
__global__ __launch_bounds__(256) void mask_gemm_kernel(
        const float* __restrict__ fc1, const float* __restrict__ P,
        const float* __restrict__ bias, const float* __restrict__ epsp,
        float* __restrict__ Out, float* __restrict__ stats) {
    __shared__ float M_l[64][33];
    __shared__ float P_l[32][128];
    __shared__ float ssum[128], ssq[128];
    int b   = blockIdx.y;
    int m0  = blockIdx.x * 64;
    int tid = threadIdx.x;
    int rt4 = tid >> 4;
    int ct8 = tid & 15;
    int lrow = tid >> 2;
    int lk   = (tid & 3) * 8;
    float acc[4][8] = {};
    for (int k0 = 0; k0 < NN; k0 += 32) {
        int kc = min(32, NN - k0);
        int gr = m0 + lrow;
        #pragma unroll
        for (int j = 0; j < 8; ++j) {
            int kk = lk + j;
            float v = 0.f;
            if (kk < kc && gr < NN) {
                float f = fc1[((size_t)b * NN + gr) * NN + k0 + kk];
                v = (f != 0.f) ? 1.f : 0.f;
            }
            M_l[lrow][kk] = v;
        }
        #pragma unroll
        for (int q = 0; q < 4; ++q) {
            int fi = (q * 256 + tid) * 4;
            int kk = fi >> 7, cc = fi & 127;
            float4 pv = make_float4(0.f, 0.f, 0.f, 0.f);
            if (kk < kc) pv = *reinterpret_cast<const float4*>(&P[((size_t)b * NN + k0 + kk) * 128 + cc]);
            *reinterpret_cast<float4*>(&P_l[kk][cc]) = pv;
        }
        __syncthreads();
        #pragma unroll
        for (int k = 0; k < 32; ++k) {
            float a4[4];
            #pragma unroll
            for (int u = 0; u < 4; ++u) a4[u] = M_l[rt4 * 4 + u][k];
            float4 w0 = *reinterpret_cast<const float4*>(&P_l[k][ct8 * 8]);
            float4 w1 = *reinterpret_cast<const float4*>(&P_l[k][ct8 * 8 + 4]);
            const float w8[8] = {w0.x, w0.y, w0.z, w0.w, w1.x, w1.y, w1.z, w1.w};
            #pragma unroll
            for (int u = 0; u < 4; ++u)
                #pragma unroll
                for (int v = 0; v < 8; ++v)
                    acc[u][v] = fmaf(a4[u], w8[v], acc[u][v]);
        }
        __syncthreads();
    }
    float eps = epsp[0];
    float bsv[8];
    #pragma unroll
    for (int v = 0; v < 8; ++v) bsv[v] = bias[ct8 * 8 + v];
    float csum[8] = {}, csq[8] = {};
    #pragma unroll
    for (int u = 0; u < 4; ++u) {
        int m = m0 + rt4 * 4 + u;
        if (m < NN) {
            size_t ro = ((size_t)b * NN + m) * 128 + ct8 * 8;
            float4 p0 = *reinterpret_cast<const float4*>(&P[ro]);
            float4 p1 = *reinterpret_cast<const float4*>(&P[ro + 4]);
            const float p8[8] = {p0.x, p0.y, p0.z, p0.w, p1.x, p1.y, p1.z, p1.w};
            float o[8];
            #pragma unroll
            for (int v = 0; v < 8; ++v) o[v] = fmaf(eps, p8[v], acc[u][v]) + bsv[v];
            float4 o0 = make_float4(o[0], o[1], o[2], o[3]);
            float4 o1 = make_float4(o[4], o[5], o[6], o[7]);
            *reinterpret_cast<float4*>(&Out[ro])     = o0;
            *reinterpret_cast<float4*>(&Out[ro + 4]) = o1;
            #pragma unroll
            for (int v = 0; v < 8; ++v) { csum[v] += o[v]; csq[v] = fmaf(o[v], o[v], csq[v]); }
        }
    }
    if (tid < 128) { ssum[tid] = 0.f; ssq[tid] = 0.f; }
    __syncthreads();
    #pragma unroll
    for (int v = 0; v < 8; ++v) {
        atomicAdd(&ssum[ct8 * 8 + v], csum[v]);
        atomicAdd(&ssq[ct8 * 8 + v], csq[v]);
    }
    __syncthreads();
    if (tid < 128) { atomicAdd(&stats[tid], ssum[tid]); atomicAdd(&stats[128 + tid], ssq[tid]); }
}

// ---------------------------------------------------------------- BN params
__global__ void bnparam_kernel(const float* __restrict__ stats, const float* __restrict__ g,
                               const float* __restrict__ be, float* __restrict__ bnp) {
    int c = threadIdx.x;
    if (c >= 128) return;
    const float R = (float)ROWS_TOT;
    float m = stats[c] / R;
    float v = stats[128 + c] / R - m * m;
    v = fmaxf(v, 0.f);
    float a = g[c] * rsqrtf(v + BN_EPS_C);
    bnp[c] = a;
    bnp[128 + c] = be[c] - a * m;
}

// ---------------------------------------------------------------- final
__global__ __launch_bounds__(256) void final_kernel(
        const float* __restrict__ t4, const float* __restrict__ bnp, float* __restrict__ out) {
    int idx = blockIdx.x * blockDim.x + threadIdx.x; // one float4 each
    const int n4 = (ROWS_TOT * 128) / 4;
    if (idx >= n4) return;
    float4 x = *reinterpret_cast<const float4*>(&t4[(size_t)idx * 4]);
    int c = (idx * 4) & 127;
    float o0 = fmaxf(fmaf(x.x, bnp[c + 0], bnp[128 + c + 0]), 0.f);
    float o1 = fmaxf(fmaf(x.y, bnp[c + 1], bnp[128 + c + 1]), 0.f);
    float o2 = fmaxf(fmaf(x.z, bnp[c + 2], bnp[128 + c + 2]), 0.f);
    float o3 = fmaxf(fmaf(x.w, bnp[c + 3], bnp[128 + c + 3]), 0.f);
    *reinterpret_cast<float4*>(&out[(size_t)idx * 4]) = make_float4(o0, o1, o2, o3);
}

// ---------------------------------------------------------------- launcher
extern "C" void kernel_launch(void* const* d_in, const int* in_sizes, int n_in,
                              void* d_out, int out_size, void* d_ws, size_t ws_size,
                              hipStream_t stream) {
    const float* X      = (const float*)d_in[0];
    const float* g1_eps = (const float*)d_in[1];
    const float* g1_w1  = (const float*)d_in[2];
    const float* g1_b1  = (const float*)d_in[3];
    const float* g1_g1  = (const float*)d_in[4];
    const float* g1_be1 = (const float*)d_in[5];
    const float* g1_w2  = (const float*)d_in[6];
    const float* g1_b2  = (const float*)d_in[7];
    const float* g1_g2  = (const float*)d_in[8];
    const float* g1_be2 = (const float*)d_in[9];
    const float* g2_eps = (const float*)d_in[10];
    const float* g2_w1  = (const float*)d_in[11];
    const float* g2_b1  = (const float*)d_in[12];
    const float* g2_g1  = (const float*)d_in[13];
    const float* g2_be1 = (const float*)d_in[14];
    const float* g2_w2  = (const float*)d_in[15];
    const float* g2_b2  = (const float*)d_in[16];
    const float* g2_g2  = (const float*)d_in[17];
    const float* g2_be2 = (const float*)d_in[18];
    float* out = (float*)d_out;
    float* ws  = (float*)d_ws;

    // ws layout (floats)
    float* meanv = ws;                         // 25600
    float* invd  = ws + 25600;                 // 25600
    float* stats = ws + 51200;                 // 4*256 = 1024
    float* bnp   = ws + 52224;                 // 4*256 = 1024
    float* fc1   = ws + 53248;                 // 128*200*200 = 5,120,000
    float* bufA  = ws + 53248 + 5120000;       // 128*200*128 = 3,276,800
    float* bufB  = bufA + 3276800;             // 3,276,800

    zero_kernel<<<1, 1024, 0, stream>>>(stats, 1024);
    mean_invd_kernel<<<BB, 256, 0, stream>>>(X, meanv, invd);
    corr_kernel<<<dim3(4, 4, BB), 256, 0, stream>>>(X, meanv, invd, fc1);

    // GIN layer 1
    gemm_bw_kernel<NN, 1, false, false><<<ROWS_TOT / 64, 256, 0, stream>>>(
        fc1, g1_w1, nullptr, nullptr, bufA, nullptr);                       // P = |fc1| @ w1
    mask_gemm_kernel<<<dim3(4, BB), 256, 0, stream>>>(
        fc1, bufA, g1_b1, g1_eps, bufB, stats + 0);                         // t1
    bnparam_kernel<<<1, 128, 0, stream>>>(stats + 0, g1_g1, g1_be1, bnp + 0);
    gemm_bw_kernel<HH, 2, true, true><<<ROWS_TOT / 64, 256, 0, stream>>>(
        bufB, g1_w2, bnp + 0, g1_b2, bufA, stats + 256);                    // t2
    bnparam_kernel<<<1, 128, 0, stream>>>(stats + 256, g1_g2, g1_be2, bnp + 256);

    // GIN layer 2
    gemm_bw_kernel<HH, 2, false, false><<<ROWS_TOT / 64, 256, 0, stream>>>(
        bufA, g2_w1, bnp + 256, nullptr, bufB, nullptr);                    // Q = x1 @ w1'
    mask_gemm_kernel<<<dim3(4, BB), 256, 0, stream>>>(
        fc1, bufB, g2_b1, g2_eps, bufA, stats + 512);                       // t3
    bnparam_kernel<<<1, 128, 0, stream>>>(stats + 512, g2_g1, g2_be1, bnp + 512);
    gemm_bw_kernel<HH, 2, true, true><<<ROWS_TOT / 64, 256, 0, stream>>>(
        bufA, g2_w2, bnp + 512, g2_b2, bufB, stats + 768);                  // t4
    bnparam_kernel<<<1, 128, 0, stream>>>(stats + 768, g2_g2, g2_be2, bnp + 768);

    final_kernel<<<(ROWS_TOT * 128 / 4 + 255) / 256, 256, 0, stream>>>(bufB, bnp + 768, out);
}

// Round 2
// 344.151 us; speedup vs baseline: 1.4527x; 1.4527x over previous
//
#include <hip/hip_runtime.h>
#include <hip/hip_bf16.h>

#define BB 128
#define TT 512
#define NN 200
#define HH 128
#define NP 208   // padded ROI count for MFMA (13 x 16)
static constexpr float BN_EPS_C = 1e-5f;
static constexpr int ROWS_TOT = BB * NN; // 25600

typedef __attribute__((ext_vector_type(8))) short bf16x8;
typedef __attribute__((ext_vector_type(4))) float f32x4;
typedef __attribute__((ext_vector_type(8))) unsigned short ushort8;

__device__ inline unsigned short f2bf(float f) {
    unsigned u = __builtin_bit_cast(unsigned, f);
    unsigned r = (u + 0x7FFFu + ((u >> 16) & 1u)) >> 16;
    return (unsigned short)r;
}

// ---------------------------------------------------------------- utilities
__global__ void zero_kernel(float* __restrict__ p, int n) {
    int i = blockIdx.x * blockDim.x + threadIdx.x;
    if (i < n) p[i] = 0.f;
}

// ------------------------------------------------- center + bf16 transpose
// Per (batch, 64-ROI tile): compute mean/invd over T, then write centered
// bf16 rows xmT[b][n][t] (n-major, t-contiguous). Rows n in [200,208) = 0.
__global__ __launch_bounds__(256) void center_bf16_kernel(
        const float* __restrict__ X, unsigned short* __restrict__ xmT,
        float* __restrict__ invd) {
    int b  = blockIdx.y;
    int n0 = blockIdx.x * 64;
    int tid = threadIdx.x;
    int w = tid >> 6, l = tid & 63;
    int n = n0 + l;
    const float* xb = X + (size_t)b * TT * NN;

    __shared__ float red[2][4][64];
    float s = 0.f, ss = 0.f;
    if (n < NN) {
        #pragma unroll 4
        for (int r = 0; r < 128; ++r) {
            float v = xb[(size_t)(w * 128 + r) * NN + n];
            s += v; ss = fmaf(v, v, ss);
        }
    }
    red[0][w][l] = s; red[1][w][l] = ss;
    __syncthreads();
    float st  = red[0][0][l] + red[0][1][l] + red[0][2][l] + red[0][3][l];
    float sst = red[1][0][l] + red[1][1][l] + red[1][2][l] + red[1][3][l];
    float m = st * (1.f / TT);
    float var = sst - (float)TT * m * m;
    float id = (var > 0.f) ? rsqrtf(var) : 0.f;
    if (w == 0 && n < NN) invd[b * NN + n] = id;
    if (n >= NN) m = 0.f;

    __shared__ float tile[64][65];
    for (int c = 0; c < 8; ++c) {
        __syncthreads();
        #pragma unroll 4
        for (int r = 0; r < 16; ++r) {
            int tloc = w * 16 + r;
            float v = (n < NN) ? (xb[(size_t)(c * 64 + tloc) * NN + n] - m) : 0.f;
            tile[l][tloc] = v;
        }
        __syncthreads();
        #pragma unroll
        for (int q = 0; q < 2; ++q) {
            int idx = q * 256 + tid;
            int row = idx >> 3, c8 = idx & 7;
            int nn = n0 + row;
            if (nn < NP) {
                ushort8 pk;
                #pragma unroll
                for (int k = 0; k < 8; ++k) pk[k] = f2bf(tile[row][c8 * 8 + k]);
                *reinterpret_cast<ushort8*>(
                    &xmT[((size_t)b * NP + nn) * TT + c * 64 + c8 * 8]) = pk;
            }
        }
    }
}

// ---------------------------------------------------------------- corr MFMA
// fc1[b,i,j] = clip( (sum_t xm_i xm_t) * invd_i * invd_j , -1, 1)
__global__ __launch_bounds__(256) void corr_mfma_kernel(
        const unsigned short* __restrict__ xmT, const float* __restrict__ invd,
        float* __restrict__ fc1) {
    int b  = blockIdx.z;
    int i0 = blockIdx.x * 64;
    int j0 = blockIdx.y * 64;
    __shared__ unsigned short Al[64][72];  // 144B row stride: 16B-aligned, 2-way banks
    __shared__ unsigned short Bl[64][72];
    int tid  = threadIdx.x;
    int wave = tid >> 6, lane = tid & 63;
    int wr = wave >> 1, wc = wave & 1;
    const unsigned short* base = xmT + (size_t)b * NP * TT;

    f32x4 acc[2][2] = {};
    for (int t0 = 0; t0 < TT; t0 += 64) {
        #pragma unroll
        for (int q = 0; q < 2; ++q) {
            int idx = q * 256 + tid;
            int row = idx >> 3, c8 = idx & 7;
            int ra = min(i0 + row, NP - 1);
            int rb = min(j0 + row, NP - 1);
            ushort8 va = *reinterpret_cast<const ushort8*>(&base[(size_t)ra * TT + t0 + c8 * 8]);
            ushort8 vb = *reinterpret_cast<const ushort8*>(&base[(size_t)rb * TT + t0 + c8 * 8]);
            *reinterpret_cast<ushort8*>(&Al[row][c8 * 8]) = va;
            *reinterpret_cast<ushort8*>(&Bl[row][c8 * 8]) = vb;
        }
        __syncthreads();
        #pragma unroll
        for (int kk = 0; kk < 2; ++kk) {
            int krow = kk * 32 + (lane >> 4) * 8;
            bf16x8 a[2], bb[2];
            #pragma unroll
            for (int m2 = 0; m2 < 2; ++m2)
                a[m2] = *reinterpret_cast<const bf16x8*>(&Al[wr * 32 + m2 * 16 + (lane & 15)][krow]);
            #pragma unroll
            for (int n2 = 0; n2 < 2; ++n2)
                bb[n2] = *reinterpret_cast<const bf16x8*>(&Bl[wc * 32 + n2 * 16 + (lane & 15)][krow]);
            #pragma unroll
            for (int m2 = 0; m2 < 2; ++m2)
                #pragma unroll
                for (int n2 = 0; n2 < 2; ++n2)
                    acc[m2][n2] = __builtin_amdgcn_mfma_f32_16x16x32_bf16(
                        a[m2], bb[n2], acc[m2][n2], 0, 0, 0);
        }
        __syncthreads();
    }
    int cl = lane & 15, rh = lane >> 4;
    #pragma unroll
    for (int n2 = 0; n2 < 2; ++n2) {
        int j = j0 + wc * 32 + n2 * 16 + cl;
        if (j >= NN) continue;
        float dj = invd[b * NN + j];
        #pragma unroll
        for (int m2 = 0; m2 < 2; ++m2) {
            #pragma unroll
            for (int r = 0; r < 4; ++r) {
                int i = i0 + wr * 32 + m2 * 16 + rh * 4 + r;
                if (i >= NN) continue;
                float di = invd[b * NN + i];
                float v = acc[m2][n2][r] * di * dj;
                v = fminf(1.f, fmaxf(-1.f, v));
                fc1[((size_t)b * NN + i) * NN + j] = v;
            }
        }
    }
}

// ---------------------------------------------------------------- flat GEMM
// Out[M=25600, 128] = xform(A)[M, KDIM] @ W[KDIM, 128] (+bias) (+stats)
// XFORM: 0=identity, 1=abs, 2=bn(scale,shift)+relu  (bnp[ch], bnp[128+ch])
template<int KDIM, int XFORM, bool STATS, bool HASBIAS>
__global__ __launch_bounds__(256) void gemm_bw_kernel(
        const float* __restrict__ A, const float* __restrict__ W,
        const float* __restrict__ bnp, const float* __restrict__ bias,
        float* __restrict__ Out, float* __restrict__ stats) {
    __shared__ float A_l[64][33];
    __shared__ float W_l[32][128];
    __shared__ float ssum[128], ssq[128];
    int m0  = blockIdx.x * 64;
    int tid = threadIdx.x;
    int rt4 = tid >> 4;
    int ct8 = tid & 15;
    int lrow = tid >> 2;
    int lk   = (tid & 3) * 8;
    float acc[4][8] = {};
    for (int k0 = 0; k0 < KDIM; k0 += 32) {
        int kc = min(32, KDIM - k0);
        #pragma unroll
        for (int j = 0; j < 8; ++j) {
            int kk = lk + j;
            float v = 0.f;
            if (kk < kc) {
                v = A[(size_t)(m0 + lrow) * KDIM + k0 + kk];
                if (XFORM == 1) v = fabsf(v);
                if (XFORM == 2) { int ch = k0 + kk; v = fmaxf(fmaf(v, bnp[ch], bnp[128 + ch]), 0.f); }
            }
            A_l[lrow][kk] = v;
        }
        #pragma unroll
        for (int q = 0; q < 4; ++q) {
            int fi = (q * 256 + tid) * 4;
            int kk = fi >> 7, cc = fi & 127;
            float4 wv = make_float4(0.f, 0.f, 0.f, 0.f);
            if (kk < kc) wv = *reinterpret_cast<const float4*>(&W[(size_t)(k0 + kk) * 128 + cc]);
            *reinterpret_cast<float4*>(&W_l[kk][cc]) = wv;
        }
        __syncthreads();
        #pragma unroll
        for (int k = 0; k < 32; ++k) {
            float a4[4];
            #pragma unroll
            for (int u = 0; u < 4; ++u) a4[u] = A_l[rt4 * 4 + u][k];
            float4 w0 = *reinterpret_cast<const float4*>(&W_l[k][ct8 * 8]);
            float4 w1 = *reinterpret_cast<const float4*>(&W_l[k][ct8 * 8 + 4]);
            const float w8[8] = {w0.x, w0.y, w0.z, w0.w, w1.x, w1.y, w1.z, w1.w};
            #pragma unroll
            for (int u = 0; u < 4; ++u)
                #pragma unroll
                for (int v = 0; v < 8; ++v)
                    acc[u][v] = fmaf(a4[u], w8[v], acc[u][v]);
        }
        __syncthreads();
    }
    float bsv[8] = {};
    if (HASBIAS) {
        #pragma unroll
        for (int v = 0; v < 8; ++v) bsv[v] = bias[ct8 * 8 + v];
    }
    float csum[8] = {}, csq[8] = {};
    #pragma unroll
    for (int u = 0; u < 4; ++u) {
        int m = m0 + rt4 * 4 + u;
        float o[8];
        #pragma unroll
        for (int v = 0; v < 8; ++v) o[v] = acc[u][v] + bsv[v];
        float4 o0 = make_float4(o[0], o[1], o[2], o[3]);
        float4 o1 = make_float4(o[4], o[5], o[6], o[7]);
        *reinterpret_cast<float4*>(&Out[(size_t)m * 128 + ct8 * 8])     = o0;
        *reinterpret_cast<float4*>(&Out[(size_t)m * 128 + ct8 * 8 + 4]) = o1;
        if (STATS) {
            #pragma unroll
            for (int v = 0; v < 8; ++v) { csum[v] += o[v]; csq[v] = fmaf(o[v], o[v], csq[v]); }
        }
    }
    if (STATS) {
        if (tid < 128) { ssum[tid] = 0.f; ssq[tid] = 0.f; }
        __syncthreads();
        #pragma unroll
        for (int v = 0; v < 8; ++v) {
            atomicAdd(&ssum[ct8 * 8 + v], csum[v]);
            atomicAdd(&ssq[ct8 * 8 + v], csq[v]);
        }
        __syncthreads();
        if (tid < 128) { atomicAdd(&stats[tid], ssum[tid]); atomicAdd(&stats[128 + tid], ssq[tid]); }
    }
}

// ---------------------------------------------------------------- mask GEMM
// Out[b, m, c] = sum_k (fc1[b,m,k]!=0) * P[b,k,c] + eps*P[b,m,c] + bias[c]; + stats
__global__ __launch_bounds__(256) void mask_gemm_kernel(
        const float* __restrict__ fc1, const float* __restrict__ P,
        const float* __restrict__ bias, const float* __restrict__ epsp,
        float* __restrict__ Out, float* __restrict__ stats) {
    __shared__ float M_l[64][33];
    __shared__ float P_l[32][128];
    __shared__ float ssum[128], ssq[128];
    int b   = blockIdx.y;
    int m0  = blockIdx.x * 64;
    int tid = threadIdx.x;
    int rt4 = tid >> 4;
    int ct8 = tid & 15;
    int lrow = tid >> 2;
    int lk   = (tid & 3) * 8;
    float acc[4][8] = {};
    for (int k0 = 0; k0 < NN; k0 += 32) {
        int kc = min(32, NN - k0);
        int gr = m0 + lrow;
        #pragma unroll
        for (int j = 0; j < 8; ++j) {
            int kk = lk + j;
            float v = 0.f;
            if (kk < kc && gr < NN) {
                float f = fc1[((size_t)b * NN + gr) * NN + k0 + kk];
                v = (f != 0.f) ? 1.f : 0.f;
            }
            M_l[lrow][kk] = v;
        }
        #pragma unroll
        for (int q = 0; q < 4; ++q) {
            int fi = (q * 256 + tid) * 4;
            int kk = fi >> 7, cc = fi & 127;
            float4 pv = make_float4(0.f, 0.f, 0.f, 0.f);
            if (kk < kc) pv = *reinterpret_cast<const float4*>(&P[((size_t)b * NN + k0 + kk) * 128 + cc]);
            *reinterpret_cast<float4*>(&P_l[kk][cc]) = pv;
        }
        __syncthreads();
        #pragma unroll
        for (int k = 0; k < 32; ++k) {
            float a4[4];
            #pragma unroll
            for (int u = 0; u < 4; ++u) a4[u] = M_l[rt4 * 4 + u][k];
            float4 w0 = *reinterpret_cast<const float4*>(&P_l[k][ct8 * 8]);
            float4 w1 = *reinterpret_cast<const float4*>(&P_l[k][ct8 * 8 + 4]);
            const float w8[8] = {w0.x, w0.y, w0.z, w0.w, w1.x, w1.y, w1.z, w1.w};
            #pragma unroll
            for (int u = 0; u < 4; ++u)
                #pragma unroll
                for (int v = 0; v < 8; ++v)
                    acc[u][v] = fmaf(a4[u], w8[v], acc[u][v]);
        }
        __syncthreads();
    }
    float eps = epsp[0];
    float bsv[8];
    #pragma unroll
    for (int v = 0; v < 8; ++v) bsv[v] = bias[ct8 * 8 + v];
    float csum[8] = {}, csq[8] = {};
    #pragma unroll
    for (int u = 0; u < 4; ++u) {
        int m = m0 + rt4 * 4 + u;
        if (m < NN) {
            size_t ro = ((size_t)b * NN + m) * 128 + ct8 * 8;
            float4 p0 = *reinterpret_cast<const float4*>(&P[ro]);
            float4 p1 = *reinterpret_cast<const float4*>(&P[ro + 4]);
            const float p8[8] = {p0.x, p0.y, p0.z, p0.w, p1.x, p1.y, p1.z, p1.w};
            float o[8];
            #pragma unroll
            for (int v = 0; v < 8; ++v) o[v] = fmaf(eps, p8[v], acc[u][v]) + bsv[v];
            float4 o0 = make_float4(o[0], o[1], o[2], o[3]);
            float4 o1 = make_float4(o[4], o[5], o[6], o[7]);
            *reinterpret_cast<float4*>(&Out[ro])     = o0;
            *reinterpret_cast<float4*>(&Out[ro + 4]) = o1;
            #pragma unroll
            for (int v = 0; v < 8; ++v) { csum[v] += o[v]; csq[v] = fmaf(o[v], o[v], csq[v]); }
        }
    }
    if (tid < 128) { ssum[tid] = 0.f; ssq[tid] = 0.f; }
    __syncthreads();
    #pragma unroll
    for (int v = 0; v < 8; ++v) {
        atomicAdd(&ssum[ct8 * 8 + v], csum[v]);
        atomicAdd(&ssq[ct8 * 8 + v], csq[v]);
    }
    __syncthreads();
    if (tid < 128) { atomicAdd(&stats[tid], ssum[tid]); atomicAdd(&stats[128 + tid], ssq[tid]); }
}

// ---------------------------------------------------------------- BN params
__global__ void bnparam_kernel(const float* __restrict__ stats, const float* __restrict__ g,
                               const float* __restrict__ be, float* __restrict__ bnp) {
    int c = threadIdx.x;
    if (c >= 128) return;
    const float R = (float)ROWS_TOT;
    float m = stats[c] / R;
    float v = stats[128 + c] / R - m * m;
    v = fmaxf(v, 0.f);
    float a = g[c] * rsqrtf(v + BN_EPS_C);
    bnp[c] = a;
    bnp[128 + c] = be[c] - a * m;
}

// ---------------------------------------------------------------- final
__global__ __launch_bounds__(256) void final_kernel(
        const float* __restrict__ t4, const float* __restrict__ bnp, float* __restrict__ out) {
    int idx = blockIdx.x * blockDim.x + threadIdx.x; // one float4 each
    const int n4 = (ROWS_TOT * 128) / 4;
    if (idx >= n4) return;
    float4 x = *reinterpret_cast<const float4*>(&t4[(size_t)idx * 4]);
    int c = (idx * 4) & 127;
    float o0 = fmaxf(fmaf(x.x, bnp[c + 0], bnp[128 + c + 0]), 0.f);
    float o1 = fmaxf(fmaf(x.y, bnp[c + 1], bnp[128 + c + 1]), 0.f);
    float o2 = fmaxf(fmaf(x.z, bnp[c + 2], bnp[128 + c + 2]), 0.f);
    float o3 = fmaxf(fmaf(x.w, bnp[c + 3], bnp[128 + c + 3]), 0.f);
    *reinterpret_cast<float4*>(&out[(size_t)idx * 4]) = make_float4(o0, o1, o2, o3);
}

// ---------------------------------------------------------------- launcher
extern "C" void kernel_launch(void* const* d_in, const int* in_sizes, int n_in,
                              void* d_out, int out_size, void* d_ws, size_t ws_size,
                              hipStream_t stream) {
    const float* X      = (const float*)d_in[0];
    const float* g1_eps = (const float*)d_in[1];
    const float* g1_w1  = (const float*)d_in[2];
    const float* g1_b1  = (const float*)d_in[3];
    const float* g1_g1  = (const float*)d_in[4];
    const float* g1_be1 = (const float*)d_in[5];
    const float* g1_w2  = (const float*)d_in[6];
    const float* g1_b2  = (const float*)d_in[7];
    const float* g1_g2  = (const float*)d_in[8];
    const float* g1_be2 = (const float*)d_in[9];
    const float* g2_eps = (const float*)d_in[10];
    const float* g2_w1  = (const float*)d_in[11];
    const float* g2_b1  = (const float*)d_in[12];
    const float* g2_g1  = (const float*)d_in[13];
    const float* g2_be1 = (const float*)d_in[14];
    const float* g2_w2  = (const float*)d_in[15];
    const float* g2_b2  = (const float*)d_in[16];
    const float* g2_g2  = (const float*)d_in[17];
    const float* g2_be2 = (const float*)d_in[18];
    float* out = (float*)d_out;
    float* ws  = (float*)d_ws;

    // ws layout (floats)
    float* invd  = ws;                          // 25,600
    float* stats = ws + 25600;                  // 1,024
    float* bnp   = ws + 26624;                  // 1,024
    float* fc1   = ws + 27648;                  // 128*200*200 = 5,120,000
    float* region = ws + 27648 + 5120000;
    // xmT (bf16, 128*208*512 = 13,631,488 ushorts = 6,815,744 floats)
    // aliases bufA/bufB: dead once fc1 is written.
    unsigned short* xmT = (unsigned short*)region;
    float* bufA  = region;                      // 3,276,800
    float* bufB  = bufA + 3276800;              // 3,276,800

    zero_kernel<<<1, 1024, 0, stream>>>(stats, 1024);
    center_bf16_kernel<<<dim3(4, BB), 256, 0, stream>>>(X, xmT, invd);
    corr_mfma_kernel<<<dim3(4, 4, BB), 256, 0, stream>>>(xmT, invd, fc1);

    // GIN layer 1
    gemm_bw_kernel<NN, 1, false, false><<<ROWS_TOT / 64, 256, 0, stream>>>(
        fc1, g1_w1, nullptr, nullptr, bufA, nullptr);                       // P = |fc1| @ w1
    mask_gemm_kernel<<<dim3(4, BB), 256, 0, stream>>>(
        fc1, bufA, g1_b1, g1_eps, bufB, stats + 0);                         // t1
    bnparam_kernel<<<1, 128, 0, stream>>>(stats + 0, g1_g1, g1_be1, bnp + 0);
    gemm_bw_kernel<HH, 2, true, true><<<ROWS_TOT / 64, 256, 0, stream>>>(
        bufB, g1_w2, bnp + 0, g1_b2, bufA, stats + 256);                    // t2
    bnparam_kernel<<<1, 128, 0, stream>>>(stats + 256, g1_g2, g1_be2, bnp + 256);

    // GIN layer 2
    gemm_bw_kernel<HH, 2, false, false><<<ROWS_TOT / 64, 256, 0, stream>>>(
        bufA, g2_w1, bnp + 256, nullptr, bufB, nullptr);                    // Q = x1 @ w1'
    mask_gemm_kernel<<<dim3(4, BB), 256, 0, stream>>>(
        fc1, bufB, g2_b1, g2_eps, bufA, stats + 512);                       // t3
    bnparam_kernel<<<1, 128, 0, stream>>>(stats + 512, g2_g1, g2_be1, bnp + 512);
    gemm_bw_kernel<HH, 2, true, true><<<ROWS_TOT / 64, 256, 0, stream>>>(
        bufA, g2_w2, bnp + 512, g2_b2, bufB, stats + 768);                  // t4
    bnparam_kernel<<<1, 128, 0, stream>>>(stats + 768, g2_g2, g2_be2, bnp + 768);

    final_kernel<<<(ROWS_TOT * 128 / 4 + 255) / 256, 256, 0, stream>>>(bufB, bnp + 768, out);
}

// Round 5
// 239.531 us; speedup vs baseline: 2.0871x; 1.4368x over previous
//
#include <hip/hip_runtime.h>
#include <hip/hip_bf16.h>

#define BB 128
#define TT 512
#define NN 200
#define HH 128
#define NP 208   // padded ROI count for MFMA (13 x 16)
static constexpr float BN_EPS_C = 1e-5f;
static constexpr int ROWS_TOT = BB * NN; // 25600

typedef __attribute__((ext_vector_type(8))) short bf16x8;
typedef __attribute__((ext_vector_type(4))) float f32x4;
typedef __attribute__((ext_vector_type(8))) unsigned short ushort8;

__device__ inline unsigned short f2bf(float f) {
    unsigned u = __builtin_bit_cast(unsigned, f);
    unsigned r = (u + 0x7FFFu + ((u >> 16) & 1u)) >> 16;
    return (unsigned short)r;
}

// ---------------------------------------------------------------- utilities
__global__ void zero_kernel(float* __restrict__ p, int n) {
    int i = blockIdx.x * blockDim.x + threadIdx.x;
    if (i < n) p[i] = 0.f;
}

// ------------------------------------------------- center + bf16 transpose
__global__ __launch_bounds__(256) void center_bf16_kernel(
        const float* __restrict__ X, unsigned short* __restrict__ xmT,
        float* __restrict__ invd) {
    int b  = blockIdx.y;
    int n0 = blockIdx.x * 64;
    int tid = threadIdx.x;
    int w = tid >> 6, l = tid & 63;
    int n = n0 + l;
    const float* xb = X + (size_t)b * TT * NN;

    __shared__ float red[2][4][64];
    float s = 0.f, ss = 0.f;
    if (n < NN) {
        #pragma unroll 4
        for (int r = 0; r < 128; ++r) {
            float v = xb[(size_t)(w * 128 + r) * NN + n];
            s += v; ss = fmaf(v, v, ss);
        }
    }
    red[0][w][l] = s; red[1][w][l] = ss;
    __syncthreads();
    float st  = red[0][0][l] + red[0][1][l] + red[0][2][l] + red[0][3][l];
    float sst = red[1][0][l] + red[1][1][l] + red[1][2][l] + red[1][3][l];
    float m = st * (1.f / TT);
    float var = sst - (float)TT * m * m;
    float id = (var > 0.f) ? rsqrtf(var) : 0.f;
    if (w == 0 && n < NN) invd[b * NN + n] = id;
    if (n >= NN) m = 0.f;

    __shared__ float tile[64][65];
    for (int c = 0; c < 8; ++c) {
        __syncthreads();
        #pragma unroll 4
        for (int r = 0; r < 16; ++r) {
            int tloc = w * 16 + r;
            float v = (n < NN) ? (xb[(size_t)(c * 64 + tloc) * NN + n] - m) : 0.f;
            tile[l][tloc] = v;
        }
        __syncthreads();
        #pragma unroll
        for (int q = 0; q < 2; ++q) {
            int idx = q * 256 + tid;
            int row = idx >> 3, c8 = idx & 7;
            int nn = n0 + row;
            if (nn < NP) {
                ushort8 pk;
                #pragma unroll
                for (int k = 0; k < 8; ++k) pk[k] = f2bf(tile[row][c8 * 8 + k]);
                *reinterpret_cast<ushort8*>(
                    &xmT[((size_t)b * NP + nn) * TT + c * 64 + c8 * 8]) = pk;
            }
        }
    }
}

// ---------------------------------------------------------------- corr MFMA
__global__ __launch_bounds__(256) void corr_mfma_kernel(
        const unsigned short* __restrict__ xmT, const float* __restrict__ invd,
        float* __restrict__ fc1) {
    int b  = blockIdx.z;
    int i0 = blockIdx.x * 64;
    int j0 = blockIdx.y * 64;
    __shared__ unsigned short Al[64][72];
    __shared__ unsigned short Bl[64][72];
    int tid  = threadIdx.x;
    int wave = tid >> 6, lane = tid & 63;
    int wr = wave >> 1, wc = wave & 1;
    const unsigned short* base = xmT + (size_t)b * NP * TT;

    f32x4 acc[2][2] = {};
    for (int t0 = 0; t0 < TT; t0 += 64) {
        #pragma unroll
        for (int q = 0; q < 2; ++q) {
            int idx = q * 256 + tid;
            int row = idx >> 3, c8 = idx & 7;
            int ra = min(i0 + row, NP - 1);
            int rb = min(j0 + row, NP - 1);
            ushort8 va = *reinterpret_cast<const ushort8*>(&base[(size_t)ra * TT + t0 + c8 * 8]);
            ushort8 vb = *reinterpret_cast<const ushort8*>(&base[(size_t)rb * TT + t0 + c8 * 8]);
            *reinterpret_cast<ushort8*>(&Al[row][c8 * 8]) = va;
            *reinterpret_cast<ushort8*>(&Bl[row][c8 * 8]) = vb;
        }
        __syncthreads();
        #pragma unroll
        for (int kk = 0; kk < 2; ++kk) {
            int krow = kk * 32 + (lane >> 4) * 8;
            bf16x8 a[2], bb[2];
            #pragma unroll
            for (int m2 = 0; m2 < 2; ++m2)
                a[m2] = *reinterpret_cast<const bf16x8*>(&Al[wr * 32 + m2 * 16 + (lane & 15)][krow]);
            #pragma unroll
            for (int n2 = 0; n2 < 2; ++n2)
                bb[n2] = *reinterpret_cast<const bf16x8*>(&Bl[wc * 32 + n2 * 16 + (lane & 15)][krow]);
            #pragma unroll
            for (int m2 = 0; m2 < 2; ++m2)
                #pragma unroll
                for (int n2 = 0; n2 < 2; ++n2)
                    acc[m2][n2] = __builtin_amdgcn_mfma_f32_16x16x32_bf16(
                        a[m2], bb[n2], acc[m2][n2], 0, 0, 0);
        }
        __syncthreads();
    }
    int cl = lane & 15, rh = lane >> 4;
    #pragma unroll
    for (int n2 = 0; n2 < 2; ++n2) {
        int j = j0 + wc * 32 + n2 * 16 + cl;
        if (j >= NN) continue;
        float dj = invd[b * NN + j];
        #pragma unroll
        for (int m2 = 0; m2 < 2; ++m2) {
            #pragma unroll
            for (int r = 0; r < 4; ++r) {
                int i = i0 + wr * 32 + m2 * 16 + rh * 4 + r;
                if (i >= NN) continue;
                float di = invd[b * NN + i];
                float v = acc[m2][n2][r] * di * dj;
                v = fminf(1.f, fmaxf(-1.f, v));
                fc1[((size_t)b * NN + i) * NN + j] = v;
            }
        }
    }
}

// ---------------------------------------------------------------- weight pack
// Wt_bf16[c'][k], zero-padded to KP. jobs: g1_w1(200->224), g1_w2, g2_w1, g2_w2 (128)
__global__ __launch_bounds__(256) void pack_w_kernel(
        const float* __restrict__ w0, const float* __restrict__ w1,
        const float* __restrict__ w2, const float* __restrict__ w3,
        unsigned short* __restrict__ dst) {
    int i = blockIdx.x * 256 + threadIdx.x;
    const float* src; int rel, KP, KD, base;
    if (i < 28672)      { src = w0; rel = i;         KP = 224; KD = 200; base = 0; }
    else if (i < 45056) { src = w1; rel = i - 28672; KP = 128; KD = 128; base = 28672; }
    else if (i < 61440) { src = w2; rel = i - 45056; KP = 128; KD = 128; base = 45056; }
    else if (i < 77824) { src = w3; rel = i - 61440; KP = 128; KD = 128; base = 61440; }
    else return;
    int row = rel / KP, k = rel % KP;
    dst[base + rel] = (k < KD) ? f2bf(src[(size_t)k * 128 + row]) : (unsigned short)0;
}

// ---------------------------------------------------------------- column sums
// colsum1[b,c] = sum_m |fc1[b,m,c]|
__global__ __launch_bounds__(256) void colsum_abs_kernel(
        const float* __restrict__ fc1, float* __restrict__ cs) {
    int b = blockIdx.x, c = threadIdx.x;
    if (c >= NN) return;
    float s = 0.f;
    #pragma unroll 4
    for (int m = 0; m < NN; ++m) s += fabsf(fc1[((size_t)b * NN + m) * NN + c]);
    cs[b * NN + c] = s;
}

// colsum2[b,c] = sum_n relu(bn(h[b,n,c]))
__global__ __launch_bounds__(128) void colsum_bn_kernel(
        const float* __restrict__ h, const float* __restrict__ bnp, float* __restrict__ cs) {
    int b = blockIdx.x, c = threadIdx.x;
    float a = bnp[c], sh = bnp[128 + c];
    float s = 0.f;
    #pragma unroll 4
    for (int n = 0; n < NN; ++n)
        s += fmaxf(fmaf(h[((size_t)b * NN + n) * 128 + c], a, sh), 0.f);
    cs[b * 128 + c] = s;
}

// ---------------------------------------------------------------- small GEMM
// T[b,c'] = bias[c'] + sum_k cs[b,k] * W[k,c']   (f32, per-batch block)
__global__ __launch_bounds__(128) void smallT_kernel(
        const float* __restrict__ cs, int ld, int KD, const float* __restrict__ W,
        const float* __restrict__ bias, float* __restrict__ T) {
    int b = blockIdx.x, c = threadIdx.x;
    float acc = bias[c];
    #pragma unroll 4
    for (int k = 0; k < KD; ++k)
        acc = fmaf(cs[b * ld + k], W[(size_t)k * 128 + c], acc);
    T[b * 128 + c] = acc;
}

// ---------------------------------------------------------------- MFMA GEMM
// Out[r, c'] = (WITH_T ? T[b(r),c'] + eps * acc : acc + bias[c'])
//   acc = sum_k xform(A[r,k]) * Worig[k,c'], Wp = packed bf16 [c'][KP]
// XFORM: 1 = abs, 2 = bn+relu (bnp[ch], bnp[128+ch]). stats: sum/sumsq atomics.
template<int KD, int KP, int XFORM, bool WITH_T>
__global__ __launch_bounds__(256) void mfma_gemm_kernel(
        const float* __restrict__ A, const unsigned short* __restrict__ Wp,
        const float* __restrict__ bnp, const float* __restrict__ Tvec,
        const float* __restrict__ bias, const float* __restrict__ epsp,
        float* __restrict__ Out, float* __restrict__ stats) {
    __shared__ unsigned short A_l[64][72];
    __shared__ unsigned short W_l[128][72];
    __shared__ float ssum[128], ssq[128];
    int m0 = blockIdx.x * 64;
    int tid = threadIdx.x;
    int wave = tid >> 6, lane = tid & 63;
    int wr = wave >> 1, wc = wave & 1;
    int cl = lane & 15, rh = lane >> 4;
    int arow = tid >> 2, akq = (tid & 3) * 16;
    f32x4 acc[2][4] = {};
    constexpr int KSTEPS = (KP + 63) / 64;
    for (int ks = 0; ks < KSTEPS; ++ks) {
        int k0 = ks * 64;
        float av[16];
        #pragma unroll
        for (int i = 0; i < 4; ++i) {
            int k = k0 + akq + i * 4;
            float4 f = make_float4(0.f, 0.f, 0.f, 0.f);
            if (k < KD) f = *reinterpret_cast<const float4*>(&A[(size_t)(m0 + arow) * KD + k]);
            av[i * 4 + 0] = f.x; av[i * 4 + 1] = f.y; av[i * 4 + 2] = f.z; av[i * 4 + 3] = f.w;
        }
        ushort8 p0, p1;
        #pragma unroll
        for (int j = 0; j < 8; ++j) {
            float v0 = av[j], v1 = av[8 + j];
            if (XFORM == 1) { v0 = fabsf(v0); v1 = fabsf(v1); }
            if (XFORM == 2) {
                int ch0 = k0 + akq + j, ch1 = ch0 + 8;
                v0 = fmaxf(fmaf(v0, bnp[ch0], bnp[128 + ch0]), 0.f);
                v1 = fmaxf(fmaf(v1, bnp[ch1], bnp[128 + ch1]), 0.f);
            }
            p0[j] = f2bf(v0); p1[j] = f2bf(v1);
        }
        *reinterpret_cast<ushort8*>(&A_l[arow][akq])     = p0;
        *reinterpret_cast<ushort8*>(&A_l[arow][akq + 8]) = p1;
        #pragma unroll
        for (int q = 0; q < 4; ++q) {
            int v8 = q * 256 + tid;
            int row = v8 >> 3, kq = (v8 & 7) * 8;
            ushort8 w = {0, 0, 0, 0, 0, 0, 0, 0};
            if (k0 + kq < KP)
                w = *reinterpret_cast<const ushort8*>(&Wp[(size_t)row * KP + k0 + kq]);
            *reinterpret_cast<ushort8*>(&W_l[row][kq]) = w;
        }
        __syncthreads();
        #pragma unroll
        for (int kk = 0; kk < 2; ++kk) {
            int kof = kk * 32 + rh * 8;
            bf16x8 a[2], b[4];
            #pragma unroll
            for (int m = 0; m < 2; ++m)
                a[m] = *reinterpret_cast<const bf16x8*>(&A_l[wr * 32 + m * 16 + cl][kof]);
            #pragma unroll
            for (int n = 0; n < 4; ++n)
                b[n] = *reinterpret_cast<const bf16x8*>(&W_l[wc * 64 + n * 16 + cl][kof]);
            #pragma unroll
            for (int m = 0; m < 2; ++m)
                #pragma unroll
                for (int n = 0; n < 4; ++n)
                    acc[m][n] = __builtin_amdgcn_mfma_f32_16x16x32_bf16(a[m], b[n], acc[m][n], 0, 0, 0);
        }
        __syncthreads();
    }
    float eps = WITH_T ? epsp[0] : 1.f;
    if (tid < 128) { ssum[tid] = 0.f; ssq[tid] = 0.f; }
    float cs_[4] = {0.f, 0.f, 0.f, 0.f}, cq_[4] = {0.f, 0.f, 0.f, 0.f};
    #pragma unroll
    for (int m = 0; m < 2; ++m) {
        #pragma unroll
        for (int r = 0; r < 4; ++r) {
            int i = wr * 32 + m * 16 + rh * 4 + r;
            int rg = m0 + i;
            unsigned bidx = (unsigned)rg / 200u;
            #pragma unroll
            for (int n = 0; n < 4; ++n) {
                int cp = wc * 64 + n * 16 + cl;
                float v = acc[m][n][r];
                float o = WITH_T ? fmaf(eps, v, Tvec[bidx * 128 + cp]) : (v + bias[cp]);
                Out[(size_t)rg * 128 + cp] = o;
                cs_[n] += o; cq_[n] = fmaf(o, o, cq_[n]);
            }
        }
    }
    __syncthreads();
    #pragma unroll
    for (int n = 0; n < 4; ++n) {
        int cp = wc * 64 + n * 16 + cl;
        atomicAdd(&ssum[cp], cs_[n]);
        atomicAdd(&ssq[cp], cq_[n]);
    }
    __syncthreads();
    if (tid < 128) { atomicAdd(&stats[tid], ssum[tid]); atomicAdd(&stats[128 + tid], ssq[tid]); }
}

// ---------------------------------------------------------------- BN params
__global__ void bnparam_kernel(const float* __restrict__ stats, const float* __restrict__ g,
                               const float* __restrict__ be, float* __restrict__ bnp) {
    int c = threadIdx.x;
    if (c >= 128) return;
    const float R = (float)ROWS_TOT;
    float m = stats[c] / R;
    float v = stats[128 + c] / R - m * m;
    v = fmaxf(v, 0.f);
    float a = g[c] * rsqrtf(v + BN_EPS_C);
    bnp[c] = a;
    bnp[128 + c] = be[c] - a * m;
}

// ---------------------------------------------------------------- final
__global__ __launch_bounds__(256) void final_kernel(
        const float* __restrict__ t4, const float* __restrict__ bnp, float* __restrict__ out) {
    int idx = blockIdx.x * blockDim.x + threadIdx.x;
    const int n4 = (ROWS_TOT * 128) / 4;
    if (idx >= n4) return;
    float4 x = *reinterpret_cast<const float4*>(&t4[(size_t)idx * 4]);
    int c = (idx * 4) & 127;
    float o0 = fmaxf(fmaf(x.x, bnp[c + 0], bnp[128 + c + 0]), 0.f);
    float o1 = fmaxf(fmaf(x.y, bnp[c + 1], bnp[128 + c + 1]), 0.f);
    float o2 = fmaxf(fmaf(x.z, bnp[c + 2], bnp[128 + c + 2]), 0.f);
    float o3 = fmaxf(fmaf(x.w, bnp[c + 3], bnp[128 + c + 3]), 0.f);
    *reinterpret_cast<float4*>(&out[(size_t)idx * 4]) = make_float4(o0, o1, o2, o3);
}

// ---------------------------------------------------------------- launcher
extern "C" void kernel_launch(void* const* d_in, const int* in_sizes, int n_in,
                              void* d_out, int out_size, void* d_ws, size_t ws_size,
                              hipStream_t stream) {
    const float* X      = (const float*)d_in[0];
    const float* g1_eps = (const float*)d_in[1];
    const float* g1_w1  = (const float*)d_in[2];
    const float* g1_b1  = (const float*)d_in[3];
    const float* g1_g1  = (const float*)d_in[4];
    const float* g1_be1 = (const float*)d_in[5];
    const float* g1_w2  = (const float*)d_in[6];
    const float* g1_b2  = (const float*)d_in[7];
    const float* g1_g2  = (const float*)d_in[8];
    const float* g1_be2 = (const float*)d_in[9];
    const float* g2_eps = (const float*)d_in[10];
    const float* g2_w1  = (const float*)d_in[11];
    const float* g2_b1  = (const float*)d_in[12];
    const float* g2_g1  = (const float*)d_in[13];
    const float* g2_be1 = (const float*)d_in[14];
    const float* g2_w2  = (const float*)d_in[15];
    const float* g2_b2  = (const float*)d_in[16];
    const float* g2_g2  = (const float*)d_in[17];
    const float* g2_be2 = (const float*)d_in[18];
    float* out = (float*)d_out;
    float* ws  = (float*)d_ws;

    // ws layout (floats):
    float* fc1    = ws;                        // 5,120,000
    float* region = ws + 5120000;              // 6,815,744 (xmT until corr; then bufs)
    unsigned short* xmT = (unsigned short*)region;
    float* bufA   = region;                    // 3,276,800 (h1 / h3)
    float* bufB   = bufA + 3276800;            // 3,276,800 (h2 / h4)
    float* tail   = region + 6553600;          // 262,144 available, used after corr:
    float* stats  = tail;                      // 1,024 (4 x 256)
    float* bnp    = tail + 1024;               // 1,024 (4 x 256)
    float* colsum1= tail + 2048;               // 25,600
    float* colsum2= tail + 27648;              // 16,384
    float* T1     = tail + 44032;              // 16,384
    float* T3     = tail + 60416;              // 16,384
    unsigned short* Wp = (unsigned short*)(tail + 76800); // 77,824 ushorts
    unsigned short* W1p = Wp;                  // [128][224]
    unsigned short* W2p = Wp + 28672;          // [128][128]
    unsigned short* W3p = Wp + 45056;
    unsigned short* W4p = Wp + 61440;
    float* invd   = ws + 11935744;             // 25,600

    center_bf16_kernel<<<dim3(4, BB), 256, 0, stream>>>(X, xmT, invd);
    corr_mfma_kernel<<<dim3(4, 4, BB), 256, 0, stream>>>(xmT, invd, fc1);

    // xmT dead; tail region usable now.
    zero_kernel<<<4, 256, 0, stream>>>(stats, 1024);
    pack_w_kernel<<<304, 256, 0, stream>>>(g1_w1, g1_w2, g2_w1, g2_w2, Wp);
    colsum_abs_kernel<<<BB, 256, 0, stream>>>(fc1, colsum1);
    smallT_kernel<<<BB, 128, 0, stream>>>(colsum1, NN, NN, g1_w1, g1_b1, T1);

    // GIN1 sub-layer 1: h1 = T1[b,:] + eps1 * (|fc1| @ w1)
    mfma_gemm_kernel<200, 224, 1, true><<<ROWS_TOT / 64, 256, 0, stream>>>(
        fc1, W1p, nullptr, T1, nullptr, g1_eps, bufA, stats + 0);
    bnparam_kernel<<<1, 128, 0, stream>>>(stats + 0, g1_g1, g1_be1, bnp + 0);
    // GIN1 sub-layer 2: h2 = relu(bn0(h1)) @ w2 + b2
    mfma_gemm_kernel<128, 128, 2, false><<<ROWS_TOT / 64, 256, 0, stream>>>(
        bufA, W2p, bnp + 0, nullptr, g1_b2, nullptr, bufB, stats + 256);
    bnparam_kernel<<<1, 128, 0, stream>>>(stats + 256, g1_g2, g1_be2, bnp + 256);

    // GIN2 sub-layer 1: x2 = relu(bn1(h2)); h3 = T3[b,:] + eps2 * (x2 @ w1')
    colsum_bn_kernel<<<BB, 128, 0, stream>>>(bufB, bnp + 256, colsum2);
    smallT_kernel<<<BB, 128, 0, stream>>>(colsum2, 128, 128, g2_w1, g2_b1, T3);
    mfma_gemm_kernel<128, 128, 2, true><<<ROWS_TOT / 64, 256, 0, stream>>>(
        bufB, W3p, bnp + 256, T3, nullptr, g2_eps, bufA, stats + 512);
    bnparam_kernel<<<1, 128, 0, stream>>>(stats + 512, g2_g1, g2_be1, bnp + 512);
    // GIN2 sub-layer 2: h4 = relu(bn2(h3)) @ w2' + b2'
    mfma_gemm_kernel<128, 128, 2, false><<<ROWS_TOT / 64, 256, 0, stream>>>(
        bufA, W4p, bnp + 512, nullptr, g2_b2, nullptr, bufB, stats + 768);
    bnparam_kernel<<<1, 128, 0, stream>>>(stats + 768, g2_g2, g2_be2, bnp + 768);

    final_kernel<<<(ROWS_TOT * 128 / 4 + 255) / 256, 256, 0, stream>>>(bufB, bnp + 768, out);
}

// Round 6
// 202.913 us; speedup vs baseline: 2.4638x; 1.1805x over previous
//
#include <hip/hip_runtime.h>
#include <hip/hip_bf16.h>

#define BB 128
#define TT 512
#define NN 200
#define HH 128
#define NP 208   // padded ROI count for MFMA (13 x 16)
static constexpr float BN_EPS_C = 1e-5f;
static constexpr int ROWS_TOT = BB * NN; // 25600

typedef __attribute__((ext_vector_type(8))) short bf16x8;
typedef __attribute__((ext_vector_type(4))) float f32x4;
typedef __attribute__((ext_vector_type(8))) unsigned short ushort8;

__device__ inline unsigned short f2bf(float f) {
    unsigned u = __builtin_bit_cast(unsigned, f);
    unsigned r = (u + 0x7FFFu + ((u >> 16) & 1u)) >> 16;
    return (unsigned short)r;
}

// ------------------------------------------------- center + bf16 transpose
// Single-pass, register-resident: each thread holds 128 X values (its
// t-quarter for its column), sums from registers, transposes via LDS.
__global__ __launch_bounds__(256) void center_bf16_kernel(
        const float* __restrict__ X, unsigned short* __restrict__ xmT,
        float* __restrict__ invd) {
    int b  = blockIdx.y;
    int n0 = blockIdx.x * 64;
    int tid = threadIdx.x;
    int w = tid >> 6, l = tid & 63;
    int n = n0 + l;
    bool act = (n < NN);
    const float* xb = X + (size_t)b * TT * NN;

    // load xv[c*16+r] = X[t = c*64 + w*16 + r][n] — coalesced per wave,
    // 128 independent loads in flight.
    float xv[128];
    #pragma unroll
    for (int c = 0; c < 8; ++c)
        #pragma unroll
        for (int r = 0; r < 16; ++r)
            xv[c * 16 + r] = act ? xb[(size_t)(c * 64 + w * 16 + r) * NN + n] : 0.f;

    float s = 0.f, ss = 0.f;
    #pragma unroll
    for (int i = 0; i < 128; ++i) { s += xv[i]; ss = fmaf(xv[i], xv[i], ss); }

    __shared__ float red[2][4][64];
    red[0][w][l] = s; red[1][w][l] = ss;
    __syncthreads();
    float st  = red[0][0][l] + red[0][1][l] + red[0][2][l] + red[0][3][l];
    float sst = red[1][0][l] + red[1][1][l] + red[1][2][l] + red[1][3][l];
    float m = st * (1.f / TT);
    float var = sst - (float)TT * m * m;
    float id = (var > 0.f) ? rsqrtf(var) : 0.f;
    if (w == 0 && act) invd[b * NN + n] = id;
    if (!act) m = 0.f;

    __shared__ float tile[64][65];
    for (int c = 0; c < 8; ++c) {
        __syncthreads();
        #pragma unroll
        for (int r = 0; r < 16; ++r)
            tile[l][w * 16 + r] = xv[c * 16 + r] - m;
        __syncthreads();
        #pragma unroll
        for (int q = 0; q < 2; ++q) {
            int idx = q * 256 + tid;
            int row = idx >> 3, c8 = idx & 7;
            int nn = n0 + row;
            if (nn < NP) {
                ushort8 pk;
                #pragma unroll
                for (int k = 0; k < 8; ++k) pk[k] = f2bf(tile[row][c8 * 8 + k]);
                *reinterpret_cast<ushort8*>(
                    &xmT[((size_t)b * NP + nn) * TT + c * 64 + c8 * 8]) = pk;
            }
        }
    }
}

// ---------------------------------------------------------------- corr MFMA
__global__ __launch_bounds__(256) void corr_mfma_kernel(
        const unsigned short* __restrict__ xmT, const float* __restrict__ invd,
        float* __restrict__ fc1) {
    int b  = blockIdx.z;
    int i0 = blockIdx.x * 64;
    int j0 = blockIdx.y * 64;
    __shared__ unsigned short Al[64][72];
    __shared__ unsigned short Bl[64][72];
    int tid  = threadIdx.x;
    int wave = tid >> 6, lane = tid & 63;
    int wr = wave >> 1, wc = wave & 1;
    const unsigned short* base = xmT + (size_t)b * NP * TT;

    f32x4 acc[2][2] = {};
    for (int t0 = 0; t0 < TT; t0 += 64) {
        #pragma unroll
        for (int q = 0; q < 2; ++q) {
            int idx = q * 256 + tid;
            int row = idx >> 3, c8 = idx & 7;
            int ra = min(i0 + row, NP - 1);
            int rb = min(j0 + row, NP - 1);
            ushort8 va = *reinterpret_cast<const ushort8*>(&base[(size_t)ra * TT + t0 + c8 * 8]);
            ushort8 vb = *reinterpret_cast<const ushort8*>(&base[(size_t)rb * TT + t0 + c8 * 8]);
            *reinterpret_cast<ushort8*>(&Al[row][c8 * 8]) = va;
            *reinterpret_cast<ushort8*>(&Bl[row][c8 * 8]) = vb;
        }
        __syncthreads();
        #pragma unroll
        for (int kk = 0; kk < 2; ++kk) {
            int krow = kk * 32 + (lane >> 4) * 8;
            bf16x8 a[2], bb[2];
            #pragma unroll
            for (int m2 = 0; m2 < 2; ++m2)
                a[m2] = *reinterpret_cast<const bf16x8*>(&Al[wr * 32 + m2 * 16 + (lane & 15)][krow]);
            #pragma unroll
            for (int n2 = 0; n2 < 2; ++n2)
                bb[n2] = *reinterpret_cast<const bf16x8*>(&Bl[wc * 32 + n2 * 16 + (lane & 15)][krow]);
            #pragma unroll
            for (int m2 = 0; m2 < 2; ++m2)
                #pragma unroll
                for (int n2 = 0; n2 < 2; ++n2)
                    acc[m2][n2] = __builtin_amdgcn_mfma_f32_16x16x32_bf16(
                        a[m2], bb[n2], acc[m2][n2], 0, 0, 0);
        }
        __syncthreads();
    }
    int cl = lane & 15, rh = lane >> 4;
    #pragma unroll
    for (int n2 = 0; n2 < 2; ++n2) {
        int j = j0 + wc * 32 + n2 * 16 + cl;
        if (j >= NN) continue;
        float dj = invd[b * NN + j];
        #pragma unroll
        for (int m2 = 0; m2 < 2; ++m2) {
            #pragma unroll
            for (int r = 0; r < 4; ++r) {
                int i = i0 + wr * 32 + m2 * 16 + rh * 4 + r;
                if (i >= NN) continue;
                float di = invd[b * NN + i];
                float v = acc[m2][n2][r] * di * dj;
                v = fminf(1.f, fmaxf(-1.f, v));
                fc1[((size_t)b * NN + i) * NN + j] = v;
            }
        }
    }
}

// ---------------------------------------------------------------- weight pack
// Wt_bf16[c'][k], zero-padded to KP; also zeroes the stats block (first
// 1024 global threads) — stats consumers launch later on the same stream.
__global__ __launch_bounds__(256) void pack_w_kernel(
        const float* __restrict__ w0, const float* __restrict__ w1,
        const float* __restrict__ w2, const float* __restrict__ w3,
        unsigned short* __restrict__ dst, float* __restrict__ stats) {
    int i = blockIdx.x * 256 + threadIdx.x;
    if (i < 1024) stats[i] = 0.f;
    const float* src; int rel, KP, KD, base;
    if (i < 28672)      { src = w0; rel = i;         KP = 224; KD = 200; base = 0; }
    else if (i < 45056) { src = w1; rel = i - 28672; KP = 128; KD = 128; base = 28672; }
    else if (i < 61440) { src = w2; rel = i - 45056; KP = 128; KD = 128; base = 45056; }
    else if (i < 77824) { src = w3; rel = i - 61440; KP = 128; KD = 128; base = 61440; }
    else return;
    int row = rel / KP, k = rel % KP;
    dst[base + rel] = (k < KD) ? f2bf(src[(size_t)k * 128 + row]) : (unsigned short)0;
}

// ---------------------------------------------------------------- column sums
// colsum1[b,c] = sum_m |fc1[b,m,c]|
__global__ __launch_bounds__(256) void colsum_abs_kernel(
        const float* __restrict__ fc1, float* __restrict__ cs) {
    int b = blockIdx.x, c = threadIdx.x;
    if (c >= NN) return;
    float s = 0.f;
    #pragma unroll 4
    for (int m = 0; m < NN; ++m) s += fabsf(fc1[((size_t)b * NN + m) * NN + c]);
    cs[b * NN + c] = s;
}

// colsum2[b,c] = sum_n relu(bn(h[b,n,c]))
__global__ __launch_bounds__(128) void colsum_bn_kernel(
        const float* __restrict__ h, const float* __restrict__ bnp, float* __restrict__ cs) {
    int b = blockIdx.x, c = threadIdx.x;
    float a = bnp[c], sh = bnp[128 + c];
    float s = 0.f;
    #pragma unroll 4
    for (int n = 0; n < NN; ++n)
        s += fmaxf(fmaf(h[((size_t)b * NN + n) * 128 + c], a, sh), 0.f);
    cs[b * 128 + c] = s;
}

// ---------------------------------------------------------------- small GEMM
// T[b,c'] = bias[c'] + sum_k cs[b,k] * W[k,c']   (f32, per-batch block)
__global__ __launch_bounds__(128) void smallT_kernel(
        const float* __restrict__ cs, int ld, int KD, const float* __restrict__ W,
        const float* __restrict__ bias, float* __restrict__ T) {
    int b = blockIdx.x, c = threadIdx.x;
    float acc = bias[c];
    #pragma unroll 4
    for (int k = 0; k < KD; ++k)
        acc = fmaf(cs[b * ld + k], W[(size_t)k * 128 + c], acc);
    T[b * 128 + c] = acc;
}

// ---------------------------------------------------------------- MFMA GEMM
// Out[r, c'] = (WITH_T ? T[b(r),c'] + eps * acc : acc + bias[c'])
//   acc = sum_k xform(A[r,k]) * Worig[k,c'], Wp = packed bf16 [c'][KP]
// XFORM: 1 = abs, 2 = bn+relu (bnp[ch], bnp[128+ch]). stats: sum/sumsq atomics.
template<int KD, int KP, int XFORM, bool WITH_T>
__global__ __launch_bounds__(256) void mfma_gemm_kernel(
        const float* __restrict__ A, const unsigned short* __restrict__ Wp,
        const float* __restrict__ bnp, const float* __restrict__ Tvec,
        const float* __restrict__ bias, const float* __restrict__ epsp,
        float* __restrict__ Out, float* __restrict__ stats) {
    __shared__ unsigned short A_l[64][72];
    __shared__ unsigned short W_l[128][72];
    __shared__ float ssum[128], ssq[128];
    int m0 = blockIdx.x * 64;
    int tid = threadIdx.x;
    int wave = tid >> 6, lane = tid & 63;
    int wr = wave >> 1, wc = wave & 1;
    int cl = lane & 15, rh = lane >> 4;
    int arow = tid >> 2, akq = (tid & 3) * 16;
    f32x4 acc[2][4] = {};
    constexpr int KSTEPS = (KP + 63) / 64;
    for (int ks = 0; ks < KSTEPS; ++ks) {
        int k0 = ks * 64;
        float av[16];
        #pragma unroll
        for (int i = 0; i < 4; ++i) {
            int k = k0 + akq + i * 4;
            float4 f = make_float4(0.f, 0.f, 0.f, 0.f);
            if (k < KD) f = *reinterpret_cast<const float4*>(&A[(size_t)(m0 + arow) * KD + k]);
            av[i * 4 + 0] = f.x; av[i * 4 + 1] = f.y; av[i * 4 + 2] = f.z; av[i * 4 + 3] = f.w;
        }
        ushort8 p0, p1;
        #pragma unroll
        for (int j = 0; j < 8; ++j) {
            float v0 = av[j], v1 = av[8 + j];
            if (XFORM == 1) { v0 = fabsf(v0); v1 = fabsf(v1); }
            if (XFORM == 2) {
                int ch0 = k0 + akq + j, ch1 = ch0 + 8;
                v0 = fmaxf(fmaf(v0, bnp[ch0], bnp[128 + ch0]), 0.f);
                v1 = fmaxf(fmaf(v1, bnp[ch1], bnp[128 + ch1]), 0.f);
            }
            p0[j] = f2bf(v0); p1[j] = f2bf(v1);
        }
        *reinterpret_cast<ushort8*>(&A_l[arow][akq])     = p0;
        *reinterpret_cast<ushort8*>(&A_l[arow][akq + 8]) = p1;
        #pragma unroll
        for (int q = 0; q < 4; ++q) {
            int v8 = q * 256 + tid;
            int row = v8 >> 3, kq = (v8 & 7) * 8;
            ushort8 w = {0, 0, 0, 0, 0, 0, 0, 0};
            if (k0 + kq < KP)
                w = *reinterpret_cast<const ushort8*>(&Wp[(size_t)row * KP + k0 + kq]);
            *reinterpret_cast<ushort8*>(&W_l[row][kq]) = w;
        }
        __syncthreads();
        #pragma unroll
        for (int kk = 0; kk < 2; ++kk) {
            int kof = kk * 32 + rh * 8;
            bf16x8 a[2], b[4];
            #pragma unroll
            for (int m = 0; m < 2; ++m)
                a[m] = *reinterpret_cast<const bf16x8*>(&A_l[wr * 32 + m * 16 + cl][kof]);
            #pragma unroll
            for (int n = 0; n < 4; ++n)
                b[n] = *reinterpret_cast<const bf16x8*>(&W_l[wc * 64 + n * 16 + cl][kof]);
            #pragma unroll
            for (int m = 0; m < 2; ++m)
                #pragma unroll
                for (int n = 0; n < 4; ++n)
                    acc[m][n] = __builtin_amdgcn_mfma_f32_16x16x32_bf16(a[m], b[n], acc[m][n], 0, 0, 0);
        }
        __syncthreads();
    }
    float eps = WITH_T ? epsp[0] : 1.f;
    if (tid < 128) { ssum[tid] = 0.f; ssq[tid] = 0.f; }
    float cs_[4] = {0.f, 0.f, 0.f, 0.f}, cq_[4] = {0.f, 0.f, 0.f, 0.f};
    #pragma unroll
    for (int m = 0; m < 2; ++m) {
        #pragma unroll
        for (int r = 0; r < 4; ++r) {
            int i = wr * 32 + m * 16 + rh * 4 + r;
            int rg = m0 + i;
            unsigned bidx = (unsigned)rg / 200u;
            #pragma unroll
            for (int n = 0; n < 4; ++n) {
                int cp = wc * 64 + n * 16 + cl;
                float v = acc[m][n][r];
                float o = WITH_T ? fmaf(eps, v, Tvec[bidx * 128 + cp]) : (v + bias[cp]);
                Out[(size_t)rg * 128 + cp] = o;
                cs_[n] += o; cq_[n] = fmaf(o, o, cq_[n]);
            }
        }
    }
    __syncthreads();
    #pragma unroll
    for (int n = 0; n < 4; ++n) {
        int cp = wc * 64 + n * 16 + cl;
        atomicAdd(&ssum[cp], cs_[n]);
        atomicAdd(&ssq[cp], cq_[n]);
    }
    __syncthreads();
    if (tid < 128) { atomicAdd(&stats[tid], ssum[tid]); atomicAdd(&stats[128 + tid], ssq[tid]); }
}

// ---------------------------------------------------------------- BN params
__global__ void bnparam_kernel(const float* __restrict__ stats, const float* __restrict__ g,
                               const float* __restrict__ be, float* __restrict__ bnp) {
    int c = threadIdx.x;
    if (c >= 128) return;
    const float R = (float)ROWS_TOT;
    float m = stats[c] / R;
    float v = stats[128 + c] / R - m * m;
    v = fmaxf(v, 0.f);
    float a = g[c] * rsqrtf(v + BN_EPS_C);
    bnp[c] = a;
    bnp[128 + c] = be[c] - a * m;
}

// ---------------------------------------------------------------- final
__global__ __launch_bounds__(256) void final_kernel(
        const float* __restrict__ t4, const float* __restrict__ bnp, float* __restrict__ out) {
    int idx = blockIdx.x * blockDim.x + threadIdx.x;
    const int n4 = (ROWS_TOT * 128) / 4;
    if (idx >= n4) return;
    float4 x = *reinterpret_cast<const float4*>(&t4[(size_t)idx * 4]);
    int c = (idx * 4) & 127;
    float o0 = fmaxf(fmaf(x.x, bnp[c + 0], bnp[128 + c + 0]), 0.f);
    float o1 = fmaxf(fmaf(x.y, bnp[c + 1], bnp[128 + c + 1]), 0.f);
    float o2 = fmaxf(fmaf(x.z, bnp[c + 2], bnp[128 + c + 2]), 0.f);
    float o3 = fmaxf(fmaf(x.w, bnp[c + 3], bnp[128 + c + 3]), 0.f);
    *reinterpret_cast<float4*>(&out[(size_t)idx * 4]) = make_float4(o0, o1, o2, o3);
}

// ---------------------------------------------------------------- launcher
extern "C" void kernel_launch(void* const* d_in, const int* in_sizes, int n_in,
                              void* d_out, int out_size, void* d_ws, size_t ws_size,
                              hipStream_t stream) {
    const float* X      = (const float*)d_in[0];
    const float* g1_eps = (const float*)d_in[1];
    const float* g1_w1  = (const float*)d_in[2];
    const float* g1_b1  = (const float*)d_in[3];
    const float* g1_g1  = (const float*)d_in[4];
    const float* g1_be1 = (const float*)d_in[5];
    const float* g1_w2  = (const float*)d_in[6];
    const float* g1_b2  = (const float*)d_in[7];
    const float* g1_g2  = (const float*)d_in[8];
    const float* g1_be2 = (const float*)d_in[9];
    const float* g2_eps = (const float*)d_in[10];
    const float* g2_w1  = (const float*)d_in[11];
    const float* g2_b1  = (const float*)d_in[12];
    const float* g2_g1  = (const float*)d_in[13];
    const float* g2_be1 = (const float*)d_in[14];
    const float* g2_w2  = (const float*)d_in[15];
    const float* g2_b2  = (const float*)d_in[16];
    const float* g2_g2  = (const float*)d_in[17];
    const float* g2_be2 = (const float*)d_in[18];
    float* out = (float*)d_out;
    float* ws  = (float*)d_ws;

    // ws layout (floats):
    float* fc1    = ws;                        // 5,120,000
    float* region = ws + 5120000;              // 6,815,744 (xmT until corr; then bufs)
    unsigned short* xmT = (unsigned short*)region;
    float* bufA   = region;                    // 3,276,800 (h1 / h3)
    float* bufB   = bufA + 3276800;            // 3,276,800 (h2 / h4)
    float* tail   = region + 6553600;          // 262,144 available, used after corr:
    float* stats  = tail;                      // 1,024 (4 x 256)
    float* bnp    = tail + 1024;               // 1,024 (4 x 256)
    float* colsum1= tail + 2048;               // 25,600
    float* colsum2= tail + 27648;              // 16,384
    float* T1     = tail + 44032;              // 16,384
    float* T3     = tail + 60416;              // 16,384
    unsigned short* Wp = (unsigned short*)(tail + 76800); // 77,824 ushorts
    unsigned short* W1p = Wp;                  // [128][224]
    unsigned short* W2p = Wp + 28672;          // [128][128]
    unsigned short* W3p = Wp + 45056;
    unsigned short* W4p = Wp + 61440;
    float* invd   = ws + 11935744;             // 25,600

    center_bf16_kernel<<<dim3(4, BB), 256, 0, stream>>>(X, xmT, invd);
    corr_mfma_kernel<<<dim3(4, 4, BB), 256, 0, stream>>>(xmT, invd, fc1);

    // xmT dead; tail region usable now.
    pack_w_kernel<<<304, 256, 0, stream>>>(g1_w1, g1_w2, g2_w1, g2_w2, Wp, stats);
    colsum_abs_kernel<<<BB, 256, 0, stream>>>(fc1, colsum1);
    smallT_kernel<<<BB, 128, 0, stream>>>(colsum1, NN, NN, g1_w1, g1_b1, T1);

    // GIN1 sub-layer 1: h1 = T1[b,:] + eps1 * (|fc1| @ w1)
    mfma_gemm_kernel<200, 224, 1, true><<<ROWS_TOT / 64, 256, 0, stream>>>(
        fc1, W1p, nullptr, T1, nullptr, g1_eps, bufA, stats + 0);
    bnparam_kernel<<<1, 128, 0, stream>>>(stats + 0, g1_g1, g1_be1, bnp + 0);
    // GIN1 sub-layer 2: h2 = relu(bn0(h1)) @ w2 + b2
    mfma_gemm_kernel<128, 128, 2, false><<<ROWS_TOT / 64, 256, 0, stream>>>(
        bufA, W2p, bnp + 0, nullptr, g1_b2, nullptr, bufB, stats + 256);
    bnparam_kernel<<<1, 128, 0, stream>>>(stats + 256, g1_g2, g1_be2, bnp + 256);

    // GIN2 sub-layer 1: x2 = relu(bn1(h2)); h3 = T3[b,:] + eps2 * (x2 @ w1')
    colsum_bn_kernel<<<BB, 128, 0, stream>>>(bufB, bnp + 256, colsum2);
    smallT_kernel<<<BB, 128, 0, stream>>>(colsum2, 128, 128, g2_w1, g2_b1, T3);
    mfma_gemm_kernel<128, 128, 2, true><<<ROWS_TOT / 64, 256, 0, stream>>>(
        bufB, W3p, bnp + 256, T3, nullptr, g2_eps, bufA, stats + 512);
    bnparam_kernel<<<1, 128, 0, stream>>>(stats + 512, g2_g1, g2_be1, bnp + 512);
    // GIN2 sub-layer 2: h4 = relu(bn2(h3)) @ w2' + b2'
    mfma_gemm_kernel<128, 128, 2, false><<<ROWS_TOT / 64, 256, 0, stream>>>(
        bufA, W4p, bnp + 512, nullptr, g2_b2, nullptr, bufB, stats + 768);
    bnparam_kernel<<<1, 128, 0, stream>>>(stats + 768, g2_g2, g2_be2, bnp + 768);

    final_kernel<<<(ROWS_TOT * 128 / 4 + 255) / 256, 256, 0, stream>>>(bufB, bnp + 768, out);
}

// Round 7
// 156.953 us; speedup vs baseline: 3.1852x; 1.2928x over previous
//
#include <hip/hip_runtime.h>
#include <hip/hip_bf16.h>

#define BB 128
#define TT 512
#define NN 200
#define HH 128
#define NP 208   // padded ROI count for MFMA (13 x 16)
static constexpr float BN_EPS_C = 1e-5f;
static constexpr int ROWS_TOT = BB * NN; // 25600

typedef __attribute__((ext_vector_type(8))) short bf16x8;
typedef __attribute__((ext_vector_type(4))) float f32x4;
typedef __attribute__((ext_vector_type(8))) unsigned short ushort8;

__device__ inline unsigned short f2bf(float f) {
    unsigned u = __builtin_bit_cast(unsigned, f);
    unsigned r = (u + 0x7FFFu + ((u >> 16) & 1u)) >> 16;
    return (unsigned short)r;
}

// ------------------------------------------------- center + bf16 transpose
// 512 threads (8 waves) for occupancy; each thread holds 64 X values.
// Also zeroes colsum1 (x==0 blocks) for corr's fused column-sum atomics.
__global__ __launch_bounds__(512) void center_bf16_kernel(
        const float* __restrict__ X, unsigned short* __restrict__ xmT,
        float* __restrict__ invd, float* __restrict__ colsum1) {
    int b  = blockIdx.y;
    int n0 = blockIdx.x * 64;
    int tid = threadIdx.x;
    int w = tid >> 6, l = tid & 63;   // w in 0..7
    int n = n0 + l;
    bool act = (n < NN);
    const float* xb = X + (size_t)b * TT * NN;
    if (blockIdx.x == 0 && tid < NN) colsum1[b * NN + tid] = 0.f;

    // xv[c*8+r] = X[t = c*64 + w*8 + r][n]; coalesced, 64 loads in flight
    float xv[64];
    #pragma unroll
    for (int c = 0; c < 8; ++c)
        #pragma unroll
        for (int r = 0; r < 8; ++r)
            xv[c * 8 + r] = act ? xb[(size_t)(c * 64 + w * 8 + r) * NN + n] : 0.f;

    float s = 0.f, ss = 0.f;
    #pragma unroll
    for (int i = 0; i < 64; ++i) { s += xv[i]; ss = fmaf(xv[i], xv[i], ss); }

    __shared__ float red[2][8][64];
    red[0][w][l] = s; red[1][w][l] = ss;
    __syncthreads();
    float st = 0.f, sst = 0.f;
    #pragma unroll
    for (int k = 0; k < 8; ++k) { st += red[0][k][l]; sst += red[1][k][l]; }
    float m = st * (1.f / TT);
    float var = sst - (float)TT * m * m;
    float id = (var > 0.f) ? rsqrtf(var) : 0.f;
    if (w == 0 && act) invd[b * NN + n] = id;
    if (!act) m = 0.f;

    __shared__ float tile[64][65];
    for (int c = 0; c < 8; ++c) {
        __syncthreads();
        #pragma unroll
        for (int r = 0; r < 8; ++r)
            tile[l][w * 8 + r] = xv[c * 8 + r] - m;
        __syncthreads();
        int row = tid >> 3, c8 = tid & 7;
        int nn = n0 + row;
        if (nn < NP) {
            ushort8 pk;
            #pragma unroll
            for (int k = 0; k < 8; ++k) pk[k] = f2bf(tile[row][c8 * 8 + k]);
            *reinterpret_cast<ushort8*>(
                &xmT[((size_t)b * NP + nn) * TT + c * 64 + c8 * 8]) = pk;
        }
    }
}

// ---------------------------------------------------------------- corr MFMA
// Symmetric: only 10 upper tile-pairs; mirror-write the lower block.
// Fused colsum1[b,c] = sum_m |fc1[b,m,c]| via LDS + global atomics.
// 1D grid 1280 = 128 b x 10 tiles, XCD-swizzled for xmT L2 locality.
__global__ __launch_bounds__(256) void corr_mfma_kernel(
        const unsigned short* __restrict__ xmT, const float* __restrict__ invd,
        float* __restrict__ fc1, float* __restrict__ colsum1) {
    int bid = blockIdx.x;
    int swz = (bid & 7) * 160 + (bid >> 3);   // 1280 % 8 == 0: bijective
    int b    = swz / 10;
    int tidx = swz - b * 10;
    const int tIa[10] = {0,0,0,0,1,1,1,2,2,3};
    const int tJa[10] = {0,1,2,3,1,2,3,2,3,3};
    int ti = tIa[tidx], tj = tJa[tidx];
    int i0 = ti * 64, j0 = tj * 64;
    bool offdiag = (ti != tj);

    __shared__ unsigned short Al[64][72];
    __shared__ unsigned short Bl[64][72];
    __shared__ float colJ[64], colI[64];
    int tid  = threadIdx.x;
    int wave = tid >> 6, lane = tid & 63;
    int wr = wave >> 1, wc = wave & 1;
    const unsigned short* base = xmT + (size_t)b * NP * TT;

    f32x4 acc[2][2] = {};
    for (int t0 = 0; t0 < TT; t0 += 64) {
        #pragma unroll
        for (int q = 0; q < 2; ++q) {
            int idx = q * 256 + tid;
            int row = idx >> 3, c8 = idx & 7;
            int ra = min(i0 + row, NP - 1);
            int rb = min(j0 + row, NP - 1);
            ushort8 va = *reinterpret_cast<const ushort8*>(&base[(size_t)ra * TT + t0 + c8 * 8]);
            ushort8 vb = *reinterpret_cast<const ushort8*>(&base[(size_t)rb * TT + t0 + c8 * 8]);
            *reinterpret_cast<ushort8*>(&Al[row][c8 * 8]) = va;
            *reinterpret_cast<ushort8*>(&Bl[row][c8 * 8]) = vb;
        }
        __syncthreads();
        #pragma unroll
        for (int kk = 0; kk < 2; ++kk) {
            int krow = kk * 32 + (lane >> 4) * 8;
            bf16x8 a[2], bb[2];
            #pragma unroll
            for (int m2 = 0; m2 < 2; ++m2)
                a[m2] = *reinterpret_cast<const bf16x8*>(&Al[wr * 32 + m2 * 16 + (lane & 15)][krow]);
            #pragma unroll
            for (int n2 = 0; n2 < 2; ++n2)
                bb[n2] = *reinterpret_cast<const bf16x8*>(&Bl[wc * 32 + n2 * 16 + (lane & 15)][krow]);
            #pragma unroll
            for (int m2 = 0; m2 < 2; ++m2)
                #pragma unroll
                for (int n2 = 0; n2 < 2; ++n2)
                    acc[m2][n2] = __builtin_amdgcn_mfma_f32_16x16x32_bf16(
                        a[m2], bb[n2], acc[m2][n2], 0, 0, 0);
        }
        __syncthreads();
    }

    if (tid < 64) colJ[tid] = 0.f;
    else if (tid < 128) colI[tid - 64] = 0.f;
    __syncthreads();

    int cl = lane & 15, rh = lane >> 4;
    int jg[2]; float dj2[2];
    #pragma unroll
    for (int n2 = 0; n2 < 2; ++n2) {
        jg[n2] = j0 + wc * 32 + n2 * 16 + cl;
        dj2[n2] = (jg[n2] < NN) ? invd[b * NN + jg[n2]] : 0.f;
    }
    float di2[2][4];
    #pragma unroll
    for (int m2 = 0; m2 < 2; ++m2)
        #pragma unroll
        for (int r = 0; r < 4; ++r) {
            int i = i0 + wr * 32 + m2 * 16 + rh * 4 + r;
            di2[m2][r] = (i < NN) ? invd[b * NN + i] : 0.f;
        }

    float colIacc[2][4] = {};
    #pragma unroll
    for (int n2 = 0; n2 < 2; ++n2) {
        float sj = 0.f;
        #pragma unroll
        for (int m2 = 0; m2 < 2; ++m2) {
            float o4[4];
            #pragma unroll
            for (int r = 0; r < 4; ++r) {
                float v = acc[m2][n2][r] * di2[m2][r] * dj2[n2];
                v = fminf(1.f, fmaxf(-1.f, v));
                o4[r] = v;
                sj += fabsf(v);
                colIacc[m2][r] += fabsf(v);
            }
            if (jg[n2] < NN) {
                #pragma unroll
                for (int r = 0; r < 4; ++r) {
                    int i = i0 + wr * 32 + m2 * 16 + rh * 4 + r;
                    if (i < NN) fc1[((size_t)b * NN + i) * NN + jg[n2]] = o4[r];
                }
                if (offdiag) {
                    int ib = i0 + wr * 32 + m2 * 16 + rh * 4;
                    if (ib < NN)
                        *reinterpret_cast<float4*>(&fc1[((size_t)b * NN + jg[n2]) * NN + ib]) =
                            make_float4(o4[0], o4[1], o4[2], o4[3]);
                }
            }
        }
        atomicAdd(&colJ[wc * 32 + n2 * 16 + cl], sj);
    }
    if (offdiag) {
        #pragma unroll
        for (int m2 = 0; m2 < 2; ++m2)
            #pragma unroll
            for (int r = 0; r < 4; ++r)
                atomicAdd(&colI[wr * 32 + m2 * 16 + rh * 4 + r], colIacc[m2][r]);
    }
    __syncthreads();
    if (tid < 64) {
        int j = j0 + tid;
        if (j < NN) atomicAdd(&colsum1[b * NN + j], colJ[tid]);
        if (offdiag) {
            int i = i0 + tid;
            if (i < NN) atomicAdd(&colsum1[b * NN + i], colI[tid]);
        }
    }
}

// ---------------------------------------------------------------- weight pack
// Packs 4 weights to bf16 [c'][KP]; also zeroes stats/colsum2/T1/T3 (tail[0..50176)).
__global__ __launch_bounds__(256) void pack_w_kernel(
        const float* __restrict__ w0, const float* __restrict__ w1,
        const float* __restrict__ w2, const float* __restrict__ w3,
        unsigned short* __restrict__ dst, float* __restrict__ tailz) {
    int i = blockIdx.x * 256 + threadIdx.x;
    if (i < 50176) tailz[i] = 0.f;
    const float* src; int rel, KP, KD, base;
    if (i < 28672)      { src = w0; rel = i;         KP = 224; KD = 200; base = 0; }
    else if (i < 45056) { src = w1; rel = i - 28672; KP = 128; KD = 128; base = 28672; }
    else if (i < 61440) { src = w2; rel = i - 45056; KP = 128; KD = 128; base = 45056; }
    else if (i < 77824) { src = w3; rel = i - 61440; KP = 128; KD = 128; base = 61440; }
    else return;
    int row = rel / KP, k = rel % KP;
    dst[base + rel] = (k < KD) ? f2bf(src[(size_t)k * 128 + row]) : (unsigned short)0;
}

// ---------------------------------------------------------------- colsum_bn
// colsum2[b,c] += sum over 25 rows of relu(bn(h)); bn from stats on the fly.
__global__ __launch_bounds__(128) void colsum_bn_kernel(
        const float* __restrict__ h, const float* __restrict__ stats_in,
        const float* __restrict__ g, const float* __restrict__ be,
        float* __restrict__ cs) {
    int b = blockIdx.x, c = threadIdx.x;
    const float R = (float)ROWS_TOT;
    float mm = stats_in[c] / R;
    float vv = fmaxf(stats_in[128 + c] / R - mm * mm, 0.f);
    float a = g[c] * rsqrtf(vv + BN_EPS_C);
    float sh = be[c] - a * mm;
    int nb = blockIdx.y * 25;
    float s = 0.f;
    #pragma unroll 5
    for (int n = nb; n < nb + 25; ++n)
        s += fmaxf(fmaf(h[((size_t)b * NN + n) * 128 + c], a, sh), 0.f);
    atomicAdd(&cs[b * 128 + c], s);
}

// ---------------------------------------------------------------- small GEMM
// T[b,c'] += bias(y==0) + sum_{k in chunk} cs[b,k] * W[k,c']
__global__ __launch_bounds__(128) void smallT_kernel(
        const float* __restrict__ cs, int ld, int KD, int chunk,
        const float* __restrict__ W, const float* __restrict__ bias,
        float* __restrict__ T) {
    int b = blockIdx.x, c = threadIdx.x;
    int k0 = blockIdx.y * chunk;
    int k1 = min(KD, k0 + chunk);
    float acc = (blockIdx.y == 0) ? bias[c] : 0.f;
    for (int k = k0; k < k1; ++k)
        acc = fmaf(cs[b * ld + k], W[(size_t)k * 128 + c], acc);
    atomicAdd(&T[b * 128 + c], acc);
}

// ---------------------------------------------------------------- MFMA GEMM
// XFORM: 1 = abs; 2 = bn(from stats_in,g,be)+relu on A-load.
// Out = WITH_T ? T[b,:] + eps*acc : acc + bias. stats_out: sum/sumsq atomics.
template<int KD, int KP, int XFORM, bool WITH_T>
__global__ __launch_bounds__(256) void mfma_gemm_kernel(
        const float* __restrict__ A, const unsigned short* __restrict__ Wp,
        const float* __restrict__ stats_in, const float* __restrict__ g,
        const float* __restrict__ be, const float* __restrict__ Tvec,
        const float* __restrict__ bias, const float* __restrict__ epsp,
        float* __restrict__ Out, float* __restrict__ stats_out) {
    __shared__ unsigned short A_l[64][72];
    __shared__ unsigned short W_l[128][72];
    __shared__ float ssum[128], ssq[128];
    __shared__ float bn_a[128], bn_sh[128];
    int m0 = blockIdx.x * 64;
    int tid = threadIdx.x;
    int wave = tid >> 6, lane = tid & 63;
    int wr = wave >> 1, wc = wave & 1;
    int cl = lane & 15, rh = lane >> 4;
    int arow = tid >> 2, akq = (tid & 3) * 16;
    if (XFORM == 2) {
        if (tid < 128) {
            const float R = (float)ROWS_TOT;
            float mm = stats_in[tid] / R;
            float vv = fmaxf(stats_in[128 + tid] / R - mm * mm, 0.f);
            float aa = g[tid] * rsqrtf(vv + BN_EPS_C);
            bn_a[tid] = aa; bn_sh[tid] = be[tid] - aa * mm;
        }
        __syncthreads();
    }
    f32x4 acc[2][4] = {};
    constexpr int KSTEPS = (KP + 63) / 64;
    for (int ks = 0; ks < KSTEPS; ++ks) {
        int k0 = ks * 64;
        float av[16];
        #pragma unroll
        for (int i = 0; i < 4; ++i) {
            int k = k0 + akq + i * 4;
            float4 f = make_float4(0.f, 0.f, 0.f, 0.f);
            if (k < KD) f = *reinterpret_cast<const float4*>(&A[(size_t)(m0 + arow) * KD + k]);
            av[i * 4 + 0] = f.x; av[i * 4 + 1] = f.y; av[i * 4 + 2] = f.z; av[i * 4 + 3] = f.w;
        }
        ushort8 p0, p1;
        #pragma unroll
        for (int j = 0; j < 8; ++j) {
            float v0 = av[j], v1 = av[8 + j];
            if (XFORM == 1) { v0 = fabsf(v0); v1 = fabsf(v1); }
            if (XFORM == 2) {
                int ch0 = k0 + akq + j, ch1 = ch0 + 8;
                v0 = fmaxf(fmaf(v0, bn_a[ch0], bn_sh[ch0]), 0.f);
                v1 = fmaxf(fmaf(v1, bn_a[ch1], bn_sh[ch1]), 0.f);
            }
            p0[j] = f2bf(v0); p1[j] = f2bf(v1);
        }
        *reinterpret_cast<ushort8*>(&A_l[arow][akq])     = p0;
        *reinterpret_cast<ushort8*>(&A_l[arow][akq + 8]) = p1;
        #pragma unroll
        for (int q = 0; q < 4; ++q) {
            int v8 = q * 256 + tid;
            int row = v8 >> 3, kq = (v8 & 7) * 8;
            ushort8 w = {0, 0, 0, 0, 0, 0, 0, 0};
            if (k0 + kq < KP)
                w = *reinterpret_cast<const ushort8*>(&Wp[(size_t)row * KP + k0 + kq]);
            *reinterpret_cast<ushort8*>(&W_l[row][kq]) = w;
        }
        __syncthreads();
        #pragma unroll
        for (int kk = 0; kk < 2; ++kk) {
            int kof = kk * 32 + rh * 8;
            bf16x8 a[2], bb[4];
            #pragma unroll
            for (int m = 0; m < 2; ++m)
                a[m] = *reinterpret_cast<const bf16x8*>(&A_l[wr * 32 + m * 16 + cl][kof]);
            #pragma unroll
            for (int n = 0; n < 4; ++n)
                bb[n] = *reinterpret_cast<const bf16x8*>(&W_l[wc * 64 + n * 16 + cl][kof]);
            #pragma unroll
            for (int m = 0; m < 2; ++m)
                #pragma unroll
                for (int n = 0; n < 4; ++n)
                    acc[m][n] = __builtin_amdgcn_mfma_f32_16x16x32_bf16(a[m], bb[n], acc[m][n], 0, 0, 0);
        }
        __syncthreads();
    }
    float eps = WITH_T ? epsp[0] : 1.f;
    if (tid < 128) { ssum[tid] = 0.f; ssq[tid] = 0.f; }
    float cs_[4] = {0.f, 0.f, 0.f, 0.f}, cq_[4] = {0.f, 0.f, 0.f, 0.f};
    #pragma unroll
    for (int m = 0; m < 2; ++m) {
        #pragma unroll
        for (int r = 0; r < 4; ++r) {
            int i = wr * 32 + m * 16 + rh * 4 + r;
            int rg = m0 + i;
            unsigned bidx = (unsigned)rg / 200u;
            #pragma unroll
            for (int n = 0; n < 4; ++n) {
                int cp = wc * 64 + n * 16 + cl;
                float v = acc[m][n][r];
                float o = WITH_T ? fmaf(eps, v, Tvec[bidx * 128 + cp]) : (v + bias[cp]);
                Out[(size_t)rg * 128 + cp] = o;
                cs_[n] += o; cq_[n] = fmaf(o, o, cq_[n]);
            }
        }
    }
    __syncthreads();
    #pragma unroll
    for (int n = 0; n < 4; ++n) {
        int cp = wc * 64 + n * 16 + cl;
        atomicAdd(&ssum[cp], cs_[n]);
        atomicAdd(&ssq[cp], cq_[n]);
    }
    __syncthreads();
    if (tid < 128) { atomicAdd(&stats_out[tid], ssum[tid]); atomicAdd(&stats_out[128 + tid], ssq[tid]); }
}

// ---------------------------------------------------------------- final
__global__ __launch_bounds__(256) void final_kernel(
        const float* __restrict__ t4, const float* __restrict__ stats_in,
        const float* __restrict__ g, const float* __restrict__ be,
        float* __restrict__ out) {
    __shared__ float bn_a[128], bn_sh[128];
    int tid = threadIdx.x;
    if (tid < 128) {
        const float R = (float)ROWS_TOT;
        float mm = stats_in[tid] / R;
        float vv = fmaxf(stats_in[128 + tid] / R - mm * mm, 0.f);
        float aa = g[tid] * rsqrtf(vv + BN_EPS_C);
        bn_a[tid] = aa; bn_sh[tid] = be[tid] - aa * mm;
    }
    __syncthreads();
    int idx = blockIdx.x * blockDim.x + tid;
    const int n4 = (ROWS_TOT * 128) / 4;
    if (idx >= n4) return;
    float4 x = *reinterpret_cast<const float4*>(&t4[(size_t)idx * 4]);
    int c = (idx * 4) & 127;
    float o0 = fmaxf(fmaf(x.x, bn_a[c + 0], bn_sh[c + 0]), 0.f);
    float o1 = fmaxf(fmaf(x.y, bn_a[c + 1], bn_sh[c + 1]), 0.f);
    float o2 = fmaxf(fmaf(x.z, bn_a[c + 2], bn_sh[c + 2]), 0.f);
    float o3 = fmaxf(fmaf(x.w, bn_a[c + 3], bn_sh[c + 3]), 0.f);
    *reinterpret_cast<float4*>(&out[(size_t)idx * 4]) = make_float4(o0, o1, o2, o3);
}

// ---------------------------------------------------------------- launcher
extern "C" void kernel_launch(void* const* d_in, const int* in_sizes, int n_in,
                              void* d_out, int out_size, void* d_ws, size_t ws_size,
                              hipStream_t stream) {
    const float* X      = (const float*)d_in[0];
    const float* g1_eps = (const float*)d_in[1];
    const float* g1_w1  = (const float*)d_in[2];
    const float* g1_b1  = (const float*)d_in[3];
    const float* g1_g1  = (const float*)d_in[4];
    const float* g1_be1 = (const float*)d_in[5];
    const float* g1_w2  = (const float*)d_in[6];
    const float* g1_b2  = (const float*)d_in[7];
    const float* g1_g2  = (const float*)d_in[8];
    const float* g1_be2 = (const float*)d_in[9];
    const float* g2_eps = (const float*)d_in[10];
    const float* g2_w1  = (const float*)d_in[11];
    const float* g2_b1  = (const float*)d_in[12];
    const float* g2_g1  = (const float*)d_in[13];
    const float* g2_be1 = (const float*)d_in[14];
    const float* g2_w2  = (const float*)d_in[15];
    const float* g2_b2  = (const float*)d_in[16];
    const float* g2_g2  = (const float*)d_in[17];
    const float* g2_be2 = (const float*)d_in[18];
    float* out = (float*)d_out;
    float* ws  = (float*)d_ws;

    // ws layout (floats):
    float* fc1    = ws;                        // 5,120,000
    float* region = ws + 5120000;              // xmT until corr done; then bufs
    unsigned short* xmT = (unsigned short*)region;  // 13,631,488 ushorts
    float* bufA   = region;                    // 3,276,800 (h1 / h3)
    float* bufB   = bufA + 3276800;            // 3,276,800 (h2 / h4)
    float* tail   = region + 6553600;          // overlaps xmT tail: used AFTER corr
    float* stats  = tail;                      // 1,024 (4 x 256)
    float* colsum2= tail + 1024;               // 16,384
    float* T1     = tail + 17408;              // 16,384
    float* T3     = tail + 33792;              // 16,384
    unsigned short* Wp = (unsigned short*)(tail + 50176); // 77,824 ushorts
    unsigned short* W1p = Wp;                  // [128][224]
    unsigned short* W2p = Wp + 28672;          // [128][128]
    unsigned short* W3p = Wp + 45056;
    unsigned short* W4p = Wp + 61440;
    float* invd   = ws + 11935744;             // 25,600 (outside xmT)
    float* colsum1= ws + 11961344;             // 25,600 (outside xmT; zeroed by center)

    center_bf16_kernel<<<dim3(4, BB), 512, 0, stream>>>(X, xmT, invd, colsum1);
    corr_mfma_kernel<<<1280, 256, 0, stream>>>(xmT, invd, fc1, colsum1);

    // xmT dead; tail region usable now. pack_w also zeroes stats/colsum2/T1/T3.
    pack_w_kernel<<<304, 256, 0, stream>>>(g1_w1, g1_w2, g2_w1, g2_w2, Wp, tail);
    smallT_kernel<<<dim3(BB, 5), 128, 0, stream>>>(colsum1, NN, NN, 40, g1_w1, g1_b1, T1);

    // GIN1 sub-layer 1: h1 = T1[b,:] + eps1 * (|fc1| @ w1)
    mfma_gemm_kernel<200, 224, 1, true><<<ROWS_TOT / 64, 256, 0, stream>>>(
        fc1, W1p, nullptr, nullptr, nullptr, T1, nullptr, g1_eps, bufA, stats + 0);
    // GIN1 sub-layer 2: h2 = relu(bn0(h1)) @ w2 + b2
    mfma_gemm_kernel<128, 128, 2, false><<<ROWS_TOT / 64, 256, 0, stream>>>(
        bufA, W2p, stats + 0, g1_g1, g1_be1, nullptr, g1_b2, nullptr, bufB, stats + 256);

    // GIN2 sub-layer 1: x2 = relu(bn1(h2)); h3 = T3[b,:] + eps2 * (x2 @ w1')
    colsum_bn_kernel<<<dim3(BB, 8), 128, 0, stream>>>(bufB, stats + 256, g1_g2, g1_be2, colsum2);
    smallT_kernel<<<dim3(BB, 4), 128, 0, stream>>>(colsum2, 128, 128, 32, g2_w1, g2_b1, T3);
    mfma_gemm_kernel<128, 128, 2, true><<<ROWS_TOT / 64, 256, 0, stream>>>(
        bufB, W3p, stats + 256, g1_g2, g1_be2, T3, nullptr, g2_eps, bufA, stats + 512);
    // GIN2 sub-layer 2: h4 = relu(bn2(h3)) @ w2' + b2'
    mfma_gemm_kernel<128, 128, 2, false><<<ROWS_TOT / 64, 256, 0, stream>>>(
        bufA, W4p, stats + 512, g2_g1, g2_be1, nullptr, g2_b2, nullptr, bufB, stats + 768);

    final_kernel<<<(ROWS_TOT * 128 / 4 + 255) / 256, 256, 0, stream>>>(
        bufB, stats + 768, g2_g2, g2_be2, out);
}

// Round 8
// 151.289 us; speedup vs baseline: 3.3045x; 1.0374x over previous
//
#include <hip/hip_runtime.h>
#include <hip/hip_bf16.h>

#define BB 128
#define TT 512
#define NN 200
#define HH 128
#define NP 208   // padded ROI count for MFMA (13 x 16)
static constexpr float BN_EPS_C = 1e-5f;
static constexpr int ROWS_TOT = BB * NN; // 25600
#define AKP 224  // padded K for A matrix (bf16 |corr|)

typedef __attribute__((ext_vector_type(8))) short bf16x8;
typedef __attribute__((ext_vector_type(4))) float f32x4;
typedef __attribute__((ext_vector_type(8))) unsigned short ushort8;
typedef __attribute__((ext_vector_type(4))) unsigned short ushort4v;

__device__ inline unsigned short f2bf(float f) {
    unsigned u = __builtin_bit_cast(unsigned, f);
    unsigned r = (u + 0x7FFFu + ((u >> 16) & 1u)) >> 16;
    return (unsigned short)r;
}

// ------------------------------------------------- center + bf16 transpose
// 512 threads (8 waves). Also performs one-off jobs (W-pack, A-pad zero,
// stats/colsum2 zero) spread over the grid's 262K threads, and zeroes colsum1.
__global__ __launch_bounds__(512) void center_bf16_kernel(
        const float* __restrict__ X, unsigned short* __restrict__ xmT,
        float* __restrict__ invd, float* __restrict__ colsum1,
        const float* __restrict__ w0, const float* __restrict__ w1,
        const float* __restrict__ w2, const float* __restrict__ w3,
        unsigned short* __restrict__ Wp, unsigned short* __restrict__ Apad,
        float* __restrict__ stats, float* __restrict__ colsum2) {
    int b  = blockIdx.y;
    int n0 = blockIdx.x * 64;
    int tid = threadIdx.x;

    // ---- one-off fused jobs ----
    int flat = (blockIdx.y * 4 + blockIdx.x) * 512 + tid;
    if (flat < 77824) {
        const float* src; int rel, KP, KD, base;
        if (flat < 28672)      { src = w0; rel = flat;         KP = 224; KD = 200; base = 0; }
        else if (flat < 45056) { src = w1; rel = flat - 28672; KP = 128; KD = 128; base = 28672; }
        else if (flat < 61440) { src = w2; rel = flat - 45056; KP = 128; KD = 128; base = 45056; }
        else                   { src = w3; rel = flat - 61440; KP = 128; KD = 128; base = 61440; }
        int row = rel / KP, k = rel % KP;
        Wp[base + rel] = (k < KD) ? f2bf(src[(size_t)k * 128 + row]) : (unsigned short)0;
    } else if (flat < 154624) {           // zero A pad cols [200,224)
        int q = flat - 77824;             // 76,800 jobs: 25600 rows x 3 ushort8
        int row = q / 3, p = q - row * 3;
        ushort8 z = {0, 0, 0, 0, 0, 0, 0, 0};
        *reinterpret_cast<ushort8*>(&Apad[(size_t)row * AKP + 200 + p * 8]) = z;
    } else if (flat < 155648) {
        stats[flat - 154624] = 0.f;
    } else if (flat < 172032) {
        colsum2[flat - 155648] = 0.f;
    }
    if (blockIdx.x == 0 && tid < NN) colsum1[b * NN + tid] = 0.f;

    // ---- main center work ----
    int w = tid >> 6, l = tid & 63;   // w in 0..7
    int n = n0 + l;
    bool act = (n < NN);
    const float* xb = X + (size_t)b * TT * NN;

    float xv[64];
    #pragma unroll
    for (int c = 0; c < 8; ++c)
        #pragma unroll
        for (int r = 0; r < 8; ++r)
            xv[c * 8 + r] = act ? xb[(size_t)(c * 64 + w * 8 + r) * NN + n] : 0.f;

    float s = 0.f, ss = 0.f;
    #pragma unroll
    for (int i = 0; i < 64; ++i) { s += xv[i]; ss = fmaf(xv[i], xv[i], ss); }

    __shared__ float red[2][8][64];
    red[0][w][l] = s; red[1][w][l] = ss;
    __syncthreads();
    float st = 0.f, sst = 0.f;
    #pragma unroll
    for (int k = 0; k < 8; ++k) { st += red[0][k][l]; sst += red[1][k][l]; }
    float m = st * (1.f / TT);
    float var = sst - (float)TT * m * m;
    float id = (var > 0.f) ? rsqrtf(var) : 0.f;
    if (w == 0 && act) invd[b * NN + n] = id;
    if (!act) m = 0.f;

    __shared__ float tile[64][65];
    for (int c = 0; c < 8; ++c) {
        __syncthreads();
        #pragma unroll
        for (int r = 0; r < 8; ++r)
            tile[l][w * 8 + r] = xv[c * 8 + r] - m;
        __syncthreads();
        int row = tid >> 3, c8 = tid & 7;
        int nn = n0 + row;
        if (nn < NP) {
            ushort8 pk;
            #pragma unroll
            for (int k = 0; k < 8; ++k) pk[k] = f2bf(tile[row][c8 * 8 + k]);
            *reinterpret_cast<ushort8*>(
                &xmT[((size_t)b * NP + nn) * TT + c * 64 + c8 * 8]) = pk;
        }
    }
}

// ---------------------------------------------------------------- corr MFMA
// Symmetric: 10 upper tile-pairs. Output: bf16 |corr| A-matrix [b*200+r][224]
// (mirror-write vectorized covers lower+diag; scalar direct for upper offdiag)
// + fused colsum1[b,c] = sum_m |corr[b,m,c]|.
__global__ __launch_bounds__(256) void corr_mfma_kernel(
        const unsigned short* __restrict__ xmT, const float* __restrict__ invd,
        unsigned short* __restrict__ Aout, float* __restrict__ colsum1) {
    int bid = blockIdx.x;
    int swz = (bid & 7) * 160 + (bid >> 3);   // 1280 % 8 == 0: bijective
    int b    = swz / 10;
    int tidx = swz - b * 10;
    const int tIa[10] = {0,0,0,0,1,1,1,2,2,3};
    const int tJa[10] = {0,1,2,3,1,2,3,2,3,3};
    int ti = tIa[tidx], tj = tJa[tidx];
    int i0 = ti * 64, j0 = tj * 64;
    bool offdiag = (ti != tj);

    __shared__ unsigned short Al[64][72];
    __shared__ unsigned short Bl[64][72];
    __shared__ float colJ[64], colI[64];
    int tid  = threadIdx.x;
    int wave = tid >> 6, lane = tid & 63;
    int wr = wave >> 1, wc = wave & 1;
    const unsigned short* base = xmT + (size_t)b * NP * TT;

    f32x4 acc[2][2] = {};
    for (int t0 = 0; t0 < TT; t0 += 64) {
        #pragma unroll
        for (int q = 0; q < 2; ++q) {
            int idx = q * 256 + tid;
            int row = idx >> 3, c8 = idx & 7;
            int ra = min(i0 + row, NP - 1);
            int rb = min(j0 + row, NP - 1);
            ushort8 va = *reinterpret_cast<const ushort8*>(&base[(size_t)ra * TT + t0 + c8 * 8]);
            ushort8 vb = *reinterpret_cast<const ushort8*>(&base[(size_t)rb * TT + t0 + c8 * 8]);
            *reinterpret_cast<ushort8*>(&Al[row][c8 * 8]) = va;
            *reinterpret_cast<ushort8*>(&Bl[row][c8 * 8]) = vb;
        }
        __syncthreads();
        #pragma unroll
        for (int kk = 0; kk < 2; ++kk) {
            int krow = kk * 32 + (lane >> 4) * 8;
            bf16x8 a[2], bb[2];
            #pragma unroll
            for (int m2 = 0; m2 < 2; ++m2)
                a[m2] = *reinterpret_cast<const bf16x8*>(&Al[wr * 32 + m2 * 16 + (lane & 15)][krow]);
            #pragma unroll
            for (int n2 = 0; n2 < 2; ++n2)
                bb[n2] = *reinterpret_cast<const bf16x8*>(&Bl[wc * 32 + n2 * 16 + (lane & 15)][krow]);
            #pragma unroll
            for (int m2 = 0; m2 < 2; ++m2)
                #pragma unroll
                for (int n2 = 0; n2 < 2; ++n2)
                    acc[m2][n2] = __builtin_amdgcn_mfma_f32_16x16x32_bf16(
                        a[m2], bb[n2], acc[m2][n2], 0, 0, 0);
        }
        __syncthreads();
    }

    if (tid < 64) colJ[tid] = 0.f;
    else if (tid < 128) colI[tid - 64] = 0.f;
    __syncthreads();

    int cl = lane & 15, rh = lane >> 4;
    int jg[2]; float dj2[2];
    #pragma unroll
    for (int n2 = 0; n2 < 2; ++n2) {
        jg[n2] = j0 + wc * 32 + n2 * 16 + cl;
        dj2[n2] = (jg[n2] < NN) ? invd[b * NN + jg[n2]] : 0.f;
    }
    float di2[2][4];
    #pragma unroll
    for (int m2 = 0; m2 < 2; ++m2)
        #pragma unroll
        for (int r = 0; r < 4; ++r) {
            int i = i0 + wr * 32 + m2 * 16 + rh * 4 + r;
            di2[m2][r] = (i < NN) ? invd[b * NN + i] : 0.f;
        }

    float colIacc[2][4] = {};
    #pragma unroll
    for (int n2 = 0; n2 < 2; ++n2) {
        float sj = 0.f;
        #pragma unroll
        for (int m2 = 0; m2 < 2; ++m2) {
            float o4[4];
            #pragma unroll
            for (int r = 0; r < 4; ++r) {
                float v = acc[m2][n2][r] * di2[m2][r] * dj2[n2];
                v = fminf(1.f, fmaxf(-1.f, v));
                v = fabsf(v);                       // store |corr|
                o4[r] = v;
                sj += v;
                colIacc[m2][r] += v;
            }
            int ib = i0 + wr * 32 + m2 * 16 + rh * 4;
            if (jg[n2] < NN && ib < NN) {
                // vectorized "mirror": A[b*200+j][i..i+3]
                ushort4v pk;
                pk[0] = f2bf(o4[0]); pk[1] = f2bf(o4[1]);
                pk[2] = f2bf(o4[2]); pk[3] = f2bf(o4[3]);
                *reinterpret_cast<ushort4v*>(
                    &Aout[((size_t)b * NN + jg[n2]) * AKP + ib]) = pk;
            }
            if (offdiag && jg[n2] < NN) {
                #pragma unroll
                for (int r = 0; r < 4; ++r) {
                    int i = ib + r;
                    if (i < NN)
                        Aout[((size_t)b * NN + i) * AKP + jg[n2]] = f2bf(o4[r]);
                }
            }
        }
        atomicAdd(&colJ[wc * 32 + n2 * 16 + cl], sj);
    }
    if (offdiag) {
        #pragma unroll
        for (int m2 = 0; m2 < 2; ++m2)
            #pragma unroll
            for (int r = 0; r < 4; ++r)
                atomicAdd(&colI[wr * 32 + m2 * 16 + rh * 4 + r], colIacc[m2][r]);
    }
    __syncthreads();
    if (tid < 64) {
        int j = j0 + tid;
        if (j < NN) atomicAdd(&colsum1[b * NN + j], colJ[tid]);
        if (offdiag) {
            int i = i0 + tid;
            if (i < NN) atomicAdd(&colsum1[b * NN + i], colI[tid]);
        }
    }
}

// ---------------------------------------------------------------- colsum_bn
// colsum2[b,c] += sum over 25 rows of relu(bn(h)); bn from stats on the fly.
__global__ __launch_bounds__(128) void colsum_bn_kernel(
        const float* __restrict__ h, const float* __restrict__ stats_in,
        const float* __restrict__ g, const float* __restrict__ be,
        float* __restrict__ cs) {
    int b = blockIdx.x, c = threadIdx.x;
    const float R = (float)ROWS_TOT;
    float mm = stats_in[c] / R;
    float vv = fmaxf(stats_in[128 + c] / R - mm * mm, 0.f);
    float a = g[c] * rsqrtf(vv + BN_EPS_C);
    float sh = be[c] - a * mm;
    int nb = blockIdx.y * 25;
    float s = 0.f;
    #pragma unroll 5
    for (int n = nb; n < nb + 25; ++n)
        s += fmaxf(fmaf(h[((size_t)b * NN + n) * 128 + c], a, sh), 0.f);
    atomicAdd(&cs[b * 128 + c], s);
}

// ---------------------------------------------------------------- MFMA GEMM
// A: ABF16 ? bf16 [M][AKP] (pre-transformed) : f32 [M][KD] with XFORM on load.
// XFORM: 0 = none, 2 = bn(stats_in,g,be)+relu.
// WITH_T: prologue computes Tloc[b,c'] = Tb[c'] + sum_k csrc[b,k]*Wt[k,c']
//         for the block's <=2 batches; out = Tloc + eps*acc. Else out = acc+bias.
template<int KD, int KP, int XFORM, bool WITH_T, bool ABF16, int TDOT>
__global__ __launch_bounds__(256) void mfma_gemm_kernel(
        const void* __restrict__ Avoid, const unsigned short* __restrict__ Wp,
        const float* __restrict__ stats_in, const float* __restrict__ g,
        const float* __restrict__ be,
        const float* __restrict__ csrc, const float* __restrict__ Wt,
        const float* __restrict__ Tb,
        const float* __restrict__ bias, const float* __restrict__ epsp,
        float* __restrict__ Out, float* __restrict__ stats_out) {
    __shared__ unsigned short A_l[64][72];
    __shared__ unsigned short W_l[128][72];
    __shared__ float ssum[128], ssq[128];
    __shared__ float bn_a[128], bn_sh[128];
    __shared__ float Tloc[2][128];
    int m0 = blockIdx.x * 64;
    int tid = threadIdx.x;
    int wave = tid >> 6, lane = tid & 63;
    int wr = wave >> 1, wc = wave & 1;
    int cl = lane & 15, rh = lane >> 4;
    int arow = tid >> 2, akq = (tid & 3) * 16;
    int b0 = m0 / 200;
    if (XFORM == 2 && tid < 128) {
        const float R = (float)ROWS_TOT;
        float mm = stats_in[tid] / R;
        float vv = fmaxf(stats_in[128 + tid] / R - mm * mm, 0.f);
        float aa = g[tid] * rsqrtf(vv + BN_EPS_C);
        bn_a[tid] = aa; bn_sh[tid] = be[tid] - aa * mm;
    }
    if constexpr (WITH_T) {
        int bl = tid >> 7, c = tid & 127;
        int bb = min(b0 + bl, BB - 1);
        float a = Tb[c];
        for (int k = 0; k < TDOT; ++k)
            a = fmaf(csrc[bb * TDOT + k], Wt[(size_t)k * 128 + c], a);
        Tloc[bl][c] = a;
    }
    if (XFORM == 2 || WITH_T) __syncthreads();

    f32x4 acc[2][4] = {};
    constexpr int KSTEPS = (KP + 63) / 64;
    for (int ks = 0; ks < KSTEPS; ++ks) {
        int k0 = ks * 64;
        if constexpr (ABF16) {
            const unsigned short* Ab = (const unsigned short*)Avoid;
            #pragma unroll
            for (int h = 0; h < 2; ++h) {
                int kc = k0 + akq + h * 8;
                ushort8 v = {0, 0, 0, 0, 0, 0, 0, 0};
                if (kc < AKP)
                    v = *reinterpret_cast<const ushort8*>(&Ab[(size_t)(m0 + arow) * AKP + kc]);
                *reinterpret_cast<ushort8*>(&A_l[arow][akq + h * 8]) = v;
            }
        } else {
            const float* Af = (const float*)Avoid;
            float av[16];
            #pragma unroll
            for (int i = 0; i < 4; ++i) {
                int k = k0 + akq + i * 4;
                float4 f = make_float4(0.f, 0.f, 0.f, 0.f);
                if (k < KD) f = *reinterpret_cast<const float4*>(&Af[(size_t)(m0 + arow) * KD + k]);
                av[i * 4 + 0] = f.x; av[i * 4 + 1] = f.y; av[i * 4 + 2] = f.z; av[i * 4 + 3] = f.w;
            }
            ushort8 p0, p1;
            #pragma unroll
            for (int j = 0; j < 8; ++j) {
                float v0 = av[j], v1 = av[8 + j];
                if (XFORM == 2) {
                    int ch0 = k0 + akq + j, ch1 = ch0 + 8;
                    v0 = fmaxf(fmaf(v0, bn_a[ch0], bn_sh[ch0]), 0.f);
                    v1 = fmaxf(fmaf(v1, bn_a[ch1], bn_sh[ch1]), 0.f);
                }
                p0[j] = f2bf(v0); p1[j] = f2bf(v1);
            }
            *reinterpret_cast<ushort8*>(&A_l[arow][akq])     = p0;
            *reinterpret_cast<ushort8*>(&A_l[arow][akq + 8]) = p1;
        }
        #pragma unroll
        for (int q = 0; q < 4; ++q) {
            int v8 = q * 256 + tid;
            int row = v8 >> 3, kq = (v8 & 7) * 8;
            ushort8 w = {0, 0, 0, 0, 0, 0, 0, 0};
            if (k0 + kq < KP)
                w = *reinterpret_cast<const ushort8*>(&Wp[(size_t)row * KP + k0 + kq]);
            *reinterpret_cast<ushort8*>(&W_l[row][kq]) = w;
        }
        __syncthreads();
        #pragma unroll
        for (int kk = 0; kk < 2; ++kk) {
            int kof = kk * 32 + rh * 8;
            bf16x8 a[2], bb[4];
            #pragma unroll
            for (int m = 0; m < 2; ++m)
                a[m] = *reinterpret_cast<const bf16x8*>(&A_l[wr * 32 + m * 16 + cl][kof]);
            #pragma unroll
            for (int n = 0; n < 4; ++n)
                bb[n] = *reinterpret_cast<const bf16x8*>(&W_l[wc * 64 + n * 16 + cl][kof]);
            #pragma unroll
            for (int m = 0; m < 2; ++m)
                #pragma unroll
                for (int n = 0; n < 4; ++n)
                    acc[m][n] = __builtin_amdgcn_mfma_f32_16x16x32_bf16(a[m], bb[n], acc[m][n], 0, 0, 0);
        }
        __syncthreads();
    }
    float eps = WITH_T ? epsp[0] : 1.f;
    if (tid < 128) { ssum[tid] = 0.f; ssq[tid] = 0.f; }
    float cs_[4] = {0.f, 0.f, 0.f, 0.f}, cq_[4] = {0.f, 0.f, 0.f, 0.f};
    #pragma unroll
    for (int m = 0; m < 2; ++m) {
        #pragma unroll
        for (int r = 0; r < 4; ++r) {
            int i = wr * 32 + m * 16 + rh * 4 + r;
            int rg = m0 + i;
            unsigned bidx = (unsigned)rg / 200u;
            #pragma unroll
            for (int n = 0; n < 4; ++n) {
                int cp = wc * 64 + n * 16 + cl;
                float v = acc[m][n][r];
                float o = WITH_T ? fmaf(eps, v, Tloc[bidx - b0][cp]) : (v + bias[cp]);
                Out[(size_t)rg * 128 + cp] = o;
                cs_[n] += o; cq_[n] = fmaf(o, o, cq_[n]);
            }
        }
    }
    __syncthreads();
    #pragma unroll
    for (int n = 0; n < 4; ++n) {
        int cp = wc * 64 + n * 16 + cl;
        atomicAdd(&ssum[cp], cs_[n]);
        atomicAdd(&ssq[cp], cq_[n]);
    }
    __syncthreads();
    if (tid < 128) { atomicAdd(&stats_out[tid], ssum[tid]); atomicAdd(&stats_out[128 + tid], ssq[tid]); }
}

// ---------------------------------------------------------------- final
__global__ __launch_bounds__(256) void final_kernel(
        const float* __restrict__ t4, const float* __restrict__ stats_in,
        const float* __restrict__ g, const float* __restrict__ be,
        float* __restrict__ out) {
    __shared__ float bn_a[128], bn_sh[128];
    int tid = threadIdx.x;
    if (tid < 128) {
        const float R = (float)ROWS_TOT;
        float mm = stats_in[tid] / R;
        float vv = fmaxf(stats_in[128 + tid] / R - mm * mm, 0.f);
        float aa = g[tid] * rsqrtf(vv + BN_EPS_C);
        bn_a[tid] = aa; bn_sh[tid] = be[tid] - aa * mm;
    }
    __syncthreads();
    int idx = blockIdx.x * blockDim.x + tid;
    const int n4 = (ROWS_TOT * 128) / 4;
    if (idx >= n4) return;
    float4 x = *reinterpret_cast<const float4*>(&t4[(size_t)idx * 4]);
    int c = (idx * 4) & 127;
    float o0 = fmaxf(fmaf(x.x, bn_a[c + 0], bn_sh[c + 0]), 0.f);
    float o1 = fmaxf(fmaf(x.y, bn_a[c + 1], bn_sh[c + 1]), 0.f);
    float o2 = fmaxf(fmaf(x.z, bn_a[c + 2], bn_sh[c + 2]), 0.f);
    float o3 = fmaxf(fmaf(x.w, bn_a[c + 3], bn_sh[c + 3]), 0.f);
    *reinterpret_cast<float4*>(&out[(size_t)idx * 4]) = make_float4(o0, o1, o2, o3);
}

// ---------------------------------------------------------------- launcher
extern "C" void kernel_launch(void* const* d_in, const int* in_sizes, int n_in,
                              void* d_out, int out_size, void* d_ws, size_t ws_size,
                              hipStream_t stream) {
    const float* X      = (const float*)d_in[0];
    const float* g1_eps = (const float*)d_in[1];
    const float* g1_w1  = (const float*)d_in[2];
    const float* g1_b1  = (const float*)d_in[3];
    const float* g1_g1  = (const float*)d_in[4];
    const float* g1_be1 = (const float*)d_in[5];
    const float* g1_w2  = (const float*)d_in[6];
    const float* g1_b2  = (const float*)d_in[7];
    const float* g1_g2  = (const float*)d_in[8];
    const float* g1_be2 = (const float*)d_in[9];
    const float* g2_eps = (const float*)d_in[10];
    const float* g2_w1  = (const float*)d_in[11];
    const float* g2_b1  = (const float*)d_in[12];
    const float* g2_g1  = (const float*)d_in[13];
    const float* g2_be1 = (const float*)d_in[14];
    const float* g2_w2  = (const float*)d_in[15];
    const float* g2_b2  = (const float*)d_in[16];
    const float* g2_g2  = (const float*)d_in[17];
    const float* g2_be2 = (const float*)d_in[18];
    float* out = (float*)d_out;
    float* ws  = (float*)d_ws;

    // ws layout (floats):
    unsigned short* A = (unsigned short*)ws;   // 25600*224 ushorts = 2,867,200 f
    float* region = ws + 2867200;              // xmT until corr done; then bufs
    unsigned short* xmT = (unsigned short*)region;  // 13,631,488 ushorts = 6,815,744 f
    float* bufA   = region;                    // 3,276,800 (h1 / h3)
    float* bufB   = bufA + 3276800;            // 3,276,800 (h2 / h4)
    float* tail   = region + 6815744;          // after xmT (no overlap with bufs)
    float* stats  = tail;                      // 1,024 (4 x 256)
    float* colsum2= tail + 1024;               // 16,384
    unsigned short* Wp = (unsigned short*)(tail + 17408); // 77,824 ushorts = 38,912 f
    unsigned short* W1p = Wp;                  // [128][224]
    unsigned short* W2p = Wp + 28672;          // [128][128]
    unsigned short* W3p = Wp + 45056;
    unsigned short* W4p = Wp + 61440;
    float* invd   = tail + 17408 + 38912;      // 25,600
    float* colsum1= invd + 25600;              // 25,600

    // center: main work + fused {W-pack, A-pad zero, stats/colsum2 zero, colsum1 zero}
    center_bf16_kernel<<<dim3(4, BB), 512, 0, stream>>>(
        X, xmT, invd, colsum1, g1_w1, g1_w2, g2_w1, g2_w2, Wp, A, stats, colsum2);
    // corr: bf16 |corr| A-matrix + colsum1
    corr_mfma_kernel<<<1280, 256, 0, stream>>>(xmT, invd, A, colsum1);

    // GIN1 sub-layer 1: h1 = T1[b,:] + eps1 * (A @ w1), T1 computed in prologue
    mfma_gemm_kernel<224, 224, 0, true, true, 200><<<ROWS_TOT / 64, 256, 0, stream>>>(
        A, W1p, nullptr, nullptr, nullptr, colsum1, g1_w1, g1_b1,
        nullptr, g1_eps, bufA, stats + 0);
    // GIN1 sub-layer 2: h2 = relu(bn0(h1)) @ w2 + b2
    mfma_gemm_kernel<128, 128, 2, false, false, 0><<<ROWS_TOT / 64, 256, 0, stream>>>(
        bufA, W2p, stats + 0, g1_g1, g1_be1, nullptr, nullptr, nullptr,
        g1_b2, nullptr, bufB, stats + 256);

    // GIN2 sub-layer 1: colsum2 = sum relu(bn1(h2)); h3 = T3 + eps2*(x2 @ w1')
    colsum_bn_kernel<<<dim3(BB, 8), 128, 0, stream>>>(bufB, stats + 256, g1_g2, g1_be2, colsum2);
    mfma_gemm_kernel<128, 128, 2, true, false, 128><<<ROWS_TOT / 64, 256, 0, stream>>>(
        bufB, W3p, stats + 256, g1_g2, g1_be2, colsum2, g2_w1, g2_b1,
        nullptr, g2_eps, bufA, stats + 512);
    // GIN2 sub-layer 2: h4 = relu(bn2(h3)) @ w2' + b2'
    mfma_gemm_kernel<128, 128, 2, false, false, 0><<<ROWS_TOT / 64, 256, 0, stream>>>(
        bufA, W4p, stats + 512, g2_g1, g2_be1, nullptr, nullptr, nullptr,
        g2_b2, nullptr, bufB, stats + 768);

    final_kernel<<<(ROWS_TOT * 128 / 4 + 255) / 256, 256, 0, stream>>>(
        bufB, stats + 768, g2_g2, g2_be2, out);
}